// Round 3
// baseline (561.930 us; speedup 1.0000x reference)
//
#include <hip/hip_runtime.h>

#define SN_NA    800
#define SN_F     128
#define SN_G     50
#define SN_MAXP  16384
#define SN_BP    8
#define SN_CUT2  25.0f

// ---- workspace layout (bytes, all 16B-aligned) ----
#define WO_FLAG   0
#define WO_PCNT   64
#define WO_PAIRR  128
#define WO_PAIRIJ (WO_PAIRR  + SN_MAXP*4)
#define WO_M      (WO_PAIRIJ + SN_MAXP*4)
#define WO_X      (WO_M  + SN_NA*SN_F*4)
#define WO_XF     (WO_X  + SN_NA*SN_F*4)
#define WO_XF2    (WO_XF + SN_NA*SN_F*4)
#define WO_EPART  (WO_XF2 + SN_NA*SN_F*4)
#define SN_WSNEED (WO_EPART + SN_NA*4)

// scalar dtype-generic load
template <int BF>
__device__ __forceinline__ float ldx(const void* p, int idx) {
    if (BF) {
        unsigned int x = ((unsigned int)(((const unsigned short*)p)[idx])) << 16;
        float f; __builtin_memcpy(&f, &x, 4); return f;
    }
    return ((const float*)p)[idx];
}

// vector load of 8 consecutive elements (16B for bf16, 32B for f32)
template <int BF>
__device__ __forceinline__ void ld8(const void* p, int idx, float* o) {
    if (BF) {
        uint4 v = *(const uint4*)((const unsigned short*)p + idx);
        const unsigned short* u = (const unsigned short*)&v;
#pragma unroll
        for (int q = 0; q < 8; q++) {
            unsigned int b = ((unsigned int)u[q]) << 16;
            __builtin_memcpy(&o[q], &b, 4);
        }
    } else {
        const float4* f4 = (const float4*)((const float*)p + idx);
        float4 a = f4[0], b = f4[1];
        o[0]=a.x; o[1]=a.y; o[2]=a.z; o[3]=a.w;
        o[4]=b.x; o[5]=b.y; o[6]=b.z; o[7]=b.w;
    }
}

__device__ __forceinline__ float sspf(float v) {
    float sp = fmaxf(v, 0.0f) + log1pf(__expf(-fabsf(v)));
    return sp - 0.69314718055994530942f;
}

// ---------------- dtype detect + counter zeroing ----------------
__global__ void k_detect(const void* box, int* flag, int* pcnt) {
    if (threadIdx.x == 0) {
        *pcnt = 0;
        float b0 = ((const float*)box)[0];   // f32: ~2.3 ; bf16-packed pair: denormal
        *flag = !(b0 > 1e-3f && b0 < 1e3f);
    }
}

// ---------------- pair list build (i<j, min-image PBC) ----------------
template <int BF>
__device__ void build_body(const void* pos, const void* box,
                           int* pcnt, float* pairr, unsigned int* pairij) {
    int i = blockIdx.x;
    float c00 = ldx<BF>(box,0)*10.f, c01 = ldx<BF>(box,1)*10.f, c02 = ldx<BF>(box,2)*10.f;
    float c10 = ldx<BF>(box,3)*10.f, c11 = ldx<BF>(box,4)*10.f, c12 = ldx<BF>(box,5)*10.f;
    float c20 = ldx<BF>(box,6)*10.f, c21 = ldx<BF>(box,7)*10.f, c22 = ldx<BF>(box,8)*10.f;
    float det = c00*(c11*c22 - c12*c21) - c01*(c10*c22 - c12*c20) + c02*(c10*c21 - c11*c20);
    float id  = 1.0f / det;
    float i00 = (c11*c22 - c12*c21)*id, i01 = (c02*c21 - c01*c22)*id, i02 = (c01*c12 - c02*c11)*id;
    float i10 = (c12*c20 - c10*c22)*id, i11 = (c00*c22 - c02*c20)*id, i12 = (c02*c10 - c00*c12)*id;
    float i20 = (c10*c21 - c11*c20)*id, i21 = (c01*c20 - c00*c21)*id, i22 = (c00*c11 - c01*c10)*id;

    float xi = ldx<BF>(pos, i*3+0)*10.f;
    float yi = ldx<BF>(pos, i*3+1)*10.f;
    float zi = ldx<BF>(pos, i*3+2)*10.f;

    for (int j = threadIdx.x; j < SN_NA; j += 256) {
        if (j <= i) continue;
        float dx = xi - ldx<BF>(pos, j*3+0)*10.f;
        float dy = yi - ldx<BF>(pos, j*3+1)*10.f;
        float dz = zi - ldx<BF>(pos, j*3+2)*10.f;
        float fx = dx*i00 + dy*i10 + dz*i20;
        float fy = dx*i01 + dy*i11 + dz*i21;
        float fz = dx*i02 + dy*i12 + dz*i22;
        fx -= rintf(fx); fy -= rintf(fy); fz -= rintf(fz);
        float ax = fx*c00 + fy*c10 + fz*c20;
        float ay = fx*c01 + fy*c11 + fz*c21;
        float az = fx*c02 + fy*c12 + fz*c22;
        float r2 = ax*ax + ay*ay + az*az;
        if (r2 < SN_CUT2) {
            int p = atomicAdd(pcnt, 1);
            if (p < SN_MAXP) {
                pairr[p] = sqrtf(r2);
                pairij[p] = ((unsigned int)i << 16) | (unsigned int)j;
            }
        }
    }
}
__global__ void k_build(const int* flag, const void* pos, const void* box,
                        int* pcnt, float* pairr, unsigned int* pairij) {
    if (*flag) build_body<1>(pos, box, pcnt, pairr, pairij);
    else       build_body<0>(pos, box, pcnt, pairr, pairij);
}

// ---------------- x = emb[Z]; xf = x @ Win[0]; m = 0 ----------------
template <int BF>
__device__ void init_body(const int* zn, const void* emb, const void* Win,
                          float* x, float* xf, float* m, float* xs) {
    int i = blockIdx.x;
    int f = threadIdx.x;
    float v = ldx<BF>(emb, zn[i]*SN_F + f);
    x[i*SN_F + f] = v;
    m[i*SN_F + f] = 0.0f;
    xs[f] = v;
    __syncthreads();
    float acc = 0.f;
    for (int k = 0; k < SN_F; k++)
        acc = fmaf(xs[k], ldx<BF>(Win, k*SN_F + f), acc);
    xf[i*SN_F + f] = acc;
}
__global__ void k_init(const int* flag, const int* zn, const void* emb, const void* Win,
                       float* x, float* xf, float* m) {
    __shared__ float xs[SN_F];
    if (*flag) init_body<1>(zn, emb, Win, x, xf, m, xs);
    else       init_body<0>(zn, emb, Win, x, xf, m, xs);
}

// ---------------- fused filter + scatter ----------------
// Per pair p=(i,j): Wij = ssp(g(r)@Wf1+bf1)@Wf2+bf2 ;
//   m[i] += Wij * xf[j] ; m[j] += Wij * xf[i]   (f32 atomics, L2)
// 8 pairs/block, 128 threads: 16 threads per pair, 8 features per thread.
template <int BF>
__device__ void filter_body(const float* pairr, const unsigned int* pairij, const int* pcnt,
                            const void* Wf1, const void* bf1,
                            const void* Wf2, const void* bf2,
                            const float* xf, float* m, int lay,
                            float (*gs)[52], float (*hs)[SN_F], int* sij) {
    int cnt = *pcnt; if (cnt > SN_MAXP) cnt = SN_MAXP;
    int p0 = blockIdx.x * SN_BP;
    if (p0 >= cnt) return;
    int tid = threadIdx.x;
    int b  = tid >> 4;         // pair slot
    int f0 = (tid & 15) * 8;   // feature slice

    int p = p0 + b;
    bool live = (p < cnt);
    if ((tid & 15) == 0) {
        unsigned int ij = live ? pairij[p] : 0u;
        sij[b*2+0] = (int)(ij >> 16);
        sij[b*2+1] = (int)(ij & 0xFFFFu);
    }

    const float width = 5.0f / 49.0f;
    const float gamma = 0.5f / (width * width);
    for (int t = tid; t < SN_BP*52; t += 128) {
        int bb = t / 52, k = t - bb*52;
        float g = 0.0f;
        int pp = p0 + bb;
        if (k < SN_G && pp < cnt) {
            float d = pairr[pp] - width * (float)k;
            g = __expf(-gamma * d * d);
        }
        gs[bb][k] = g;
    }
    __syncthreads();

    // stage 1: h = ssp(g @ Wf1 + bf1)
    const int w1base = lay*SN_G*SN_F;
    float acc[8];
#pragma unroll
    for (int q = 0; q < 8; q++) acc[q] = 0.f;
    for (int k = 0; k < SN_G; k++) {
        float w[8]; ld8<BF>(Wf1, w1base + k*SN_F + f0, w);
        float g = gs[b][k];
#pragma unroll
        for (int q = 0; q < 8; q++) acc[q] = fmaf(g, w[q], acc[q]);
    }
    {
        float bb1[8]; ld8<BF>(bf1, lay*SN_F + f0, bb1);
#pragma unroll
        for (int q = 0; q < 8; q++) hs[b][f0+q] = sspf(acc[q] + bb1[q]);
    }
    __syncthreads();

    // stage 2: Wij = h @ Wf2 + bf2
    const int w2base = lay*SN_F*SN_F;
#pragma unroll
    for (int q = 0; q < 8; q++) acc[q] = 0.f;
    for (int k = 0; k < SN_F; k++) {
        float w[8]; ld8<BF>(Wf2, w2base + k*SN_F + f0, w);
        float h = hs[b][k];
#pragma unroll
        for (int q = 0; q < 8; q++) acc[q] = fmaf(h, w[q], acc[q]);
    }

    if (live) {
        float bb2[8]; ld8<BF>(bf2, lay*SN_F + f0, bb2);
        int i = sij[b*2+0], j = sij[b*2+1];
        const float4* xj4 = (const float4*)&xf[j*SN_F + f0];
        const float4* xi4 = (const float4*)&xf[i*SN_F + f0];
        float4 xja = xj4[0], xjb = xj4[1];
        float4 xia = xi4[0], xib = xi4[1];
        float xjv[8] = {xja.x,xja.y,xja.z,xja.w,xjb.x,xjb.y,xjb.z,xjb.w};
        float xiv[8] = {xia.x,xia.y,xia.z,xia.w,xib.x,xib.y,xib.z,xib.w};
        float* mi = &m[i*SN_F + f0];
        float* mj = &m[j*SN_F + f0];
#pragma unroll
        for (int q = 0; q < 8; q++) {
            float W = acc[q] + bb2[q];
            atomicAdd(&mi[q], W * xjv[q]);
            atomicAdd(&mj[q], W * xiv[q]);
        }
    }
}
__global__ void k_filter(const int* flag, const float* pairr, const unsigned int* pairij,
                         const int* pcnt,
                         const void* Wf1, const void* bf1, const void* Wf2, const void* bf2,
                         const float* xf, float* m, int lay) {
    __shared__ float gs[SN_BP][52];
    __shared__ float hs[SN_BP][SN_F];
    __shared__ int sij[SN_BP*2];
    if (*flag) filter_body<1>(pairr, pairij, pcnt, Wf1, bf1, Wf2, bf2, xf, m, lay, gs, hs, sij);
    else       filter_body<0>(pairr, pairij, pcnt, Wf1, bf1, Wf2, bf2, xf, m, lay, gs, hs, sij);
}

// ---------------- dense atom update: t=ssp(m@W2+b2); x+=t@W3+b3; xf=x@WinNext; m=0 ----
// 8 atoms/block, 128 threads: 16 threads/atom, 8 features/thread.
template <int BF>
__device__ void dense_body(float* m, float* x,
                           const void* W2, const void* b2,
                           const void* W3, const void* b3,
                           const void* Win, int lay, int layNext, float* xf_out,
                           float (*ms)[SN_F], float (*ts)[SN_F], float (*xs)[SN_F]) {
    int a0 = blockIdx.x * 8;
    int tid = threadIdx.x;
    int a  = tid >> 4;
    int f0 = (tid & 15) * 8;
    int atom = a0 + a;

    // stage m into LDS, zero m for next layer's scatter
    {
        float4* m4 = (float4*)&m[atom*SN_F + f0];
        float4 ma = m4[0], mb = m4[1];
        ms[a][f0+0]=ma.x; ms[a][f0+1]=ma.y; ms[a][f0+2]=ma.z; ms[a][f0+3]=ma.w;
        ms[a][f0+4]=mb.x; ms[a][f0+5]=mb.y; ms[a][f0+6]=mb.z; ms[a][f0+7]=mb.w;
        m4[0] = make_float4(0.f,0.f,0.f,0.f);
        m4[1] = make_float4(0.f,0.f,0.f,0.f);
    }
    __syncthreads();

    const int wbase = lay*SN_F*SN_F, bbase = lay*SN_F;
    float acc[8];

    // t = ssp(m @ W2 + b2)
#pragma unroll
    for (int q = 0; q < 8; q++) acc[q] = 0.f;
    for (int k = 0; k < SN_F; k++) {
        float w[8]; ld8<BF>(W2, wbase + k*SN_F + f0, w);
        float mm = ms[a][k];
#pragma unroll
        for (int q = 0; q < 8; q++) acc[q] = fmaf(mm, w[q], acc[q]);
    }
    {
        float bb[8]; ld8<BF>(b2, bbase + f0, bb);
#pragma unroll
        for (int q = 0; q < 8; q++) ts[a][f0+q] = sspf(acc[q] + bb[q]);
    }
    __syncthreads();

    // v = t @ W3 + b3 ; xnew = x + v
#pragma unroll
    for (int q = 0; q < 8; q++) acc[q] = 0.f;
    for (int k = 0; k < SN_F; k++) {
        float w[8]; ld8<BF>(W3, wbase + k*SN_F + f0, w);
        float tt = ts[a][k];
#pragma unroll
        for (int q = 0; q < 8; q++) acc[q] = fmaf(tt, w[q], acc[q]);
    }
    {
        float bb[8]; ld8<BF>(b3, bbase + f0, bb);
        float4* x4 = (float4*)&x[atom*SN_F + f0];
        float4 xa = x4[0], xb = x4[1];
        float xn[8] = {xa.x,xa.y,xa.z,xa.w,xb.x,xb.y,xb.z,xb.w};
#pragma unroll
        for (int q = 0; q < 8; q++) { xn[q] += acc[q] + bb[q]; xs[a][f0+q] = xn[q]; }
        x4[0] = make_float4(xn[0],xn[1],xn[2],xn[3]);
        x4[1] = make_float4(xn[4],xn[5],xn[6],xn[7]);
    }

    if (layNext >= 0) {
        __syncthreads();
        const int wbaseN = layNext*SN_F*SN_F;
#pragma unroll
        for (int q = 0; q < 8; q++) acc[q] = 0.f;
        for (int k = 0; k < SN_F; k++) {
            float w[8]; ld8<BF>(Win, wbaseN + k*SN_F + f0, w);
            float xx = xs[a][k];
#pragma unroll
            for (int q = 0; q < 8; q++) acc[q] = fmaf(xx, w[q], acc[q]);
        }
        float4* o4 = (float4*)&xf_out[atom*SN_F + f0];
        o4[0] = make_float4(acc[0],acc[1],acc[2],acc[3]);
        o4[1] = make_float4(acc[4],acc[5],acc[6],acc[7]);
    }
}
__global__ void k_dense(const int* flag, float* m, float* x,
                        const void* W2, const void* b2, const void* W3, const void* b3,
                        const void* Win, int lay, int layNext, float* xf_out) {
    __shared__ float ms[8][SN_F];
    __shared__ float ts[8][SN_F];
    __shared__ float xs[8][SN_F];
    if (*flag) dense_body<1>(m, x, W2, b2, W3, b3, Win, lay, layNext, xf_out, ms, ts, xs);
    else       dense_body<0>(m, x, W2, b2, W3, b3, Win, lay, layNext, xf_out, ms, ts, xs);
}

// ---------------- energy head ----------------
template <int BF>
__device__ void head_body(const float* x, const void* Wo1, const void* bo1,
                          const void* Wo2, const void* bo2, float* epart, float* xs) {
    int a0 = blockIdx.x * 2;
    int tid = threadIdx.x;
    int a = tid >> 6, fo = tid & 63;
    xs[tid]        = x[a0*SN_F + tid];
    xs[SN_F + tid] = x[(a0+1)*SN_F + tid];
    __syncthreads();
    float acc = 0.f;
    for (int k = 0; k < SN_F; k++)
        acc = fmaf(xs[a*SN_F + k], ldx<BF>(Wo1, k*64 + fo), acc);
    float h = sspf(acc + ldx<BF>(bo1, fo));
    float e = h * ldx<BF>(Wo2, fo);
#pragma unroll
    for (int off = 32; off > 0; off >>= 1) e += __shfl_down(e, off, 64);
    if (fo == 0) epart[a0 + a] = e + ldx<BF>(bo2, 0);
}
__global__ void k_head(const int* flag, const float* x,
                       const void* Wo1, const void* bo1, const void* Wo2, const void* bo2,
                       float* epart) {
    __shared__ float xs[2*SN_F];
    if (*flag) head_body<1>(x, Wo1, bo1, Wo2, bo2, epart, xs);
    else       head_body<0>(x, Wo1, bo1, Wo2, bo2, epart, xs);
}

// ---------------- final reduce + dtype-matched store ----------------
__global__ void k_reduce(const int* flag, const float* epart, void* out) {
    __shared__ float red[256];
    int tid = threadIdx.x;
    float s = 0.f;
    for (int idx = tid; idx < SN_NA; idx += 256) s += epart[idx];
    red[tid] = s;
    __syncthreads();
    for (int w = 128; w > 0; w >>= 1) {
        if (tid < w) red[tid] += red[tid + w];
        __syncthreads();
    }
    if (tid == 0) {
        float v = red[0];
        if (*flag) {
            unsigned int xbits; __builtin_memcpy(&xbits, &v, 4);
            unsigned short r = (unsigned short)((xbits + 0x7FFFu + ((xbits >> 16) & 1u)) >> 16);
            ((unsigned short*)out)[0] = r;
        } else {
            ((float*)out)[0] = v;
        }
    }
}

__global__ void k_fail(void* out) {
    ((unsigned short*)out)[0] = 0x449A;   // bf16 1234.0 sentinel
}

extern "C" void kernel_launch(void* const* d_in, const int* in_sizes, int n_in,
                              void* d_out, int out_size, void* d_ws, size_t ws_size,
                              hipStream_t stream)
{
    const void* pos = d_in[0];
    const void* box = d_in[1];
    const int*  zn  = (const int*)d_in[2];
    const void* emb = d_in[3];
    const void* Wf1 = d_in[4];
    const void* bf1 = d_in[5];
    const void* Wf2 = d_in[6];
    const void* bf2 = d_in[7];
    const void* Win = d_in[8];
    const void* W2  = d_in[9];
    const void* b2  = d_in[10];
    const void* W3  = d_in[11];
    const void* b3  = d_in[12];
    const void* Wo1 = d_in[13];
    const void* bo1 = d_in[14];
    const void* Wo2 = d_in[15];
    const void* bo2 = d_in[16];

    if (ws_size < (size_t)SN_WSNEED) {
        k_fail<<<1, 1, 0, stream>>>(d_out);
        return;
    }

    char* ws = (char*)d_ws;
    int*          flag   = (int*)         (ws + WO_FLAG);
    int*          pcnt   = (int*)         (ws + WO_PCNT);
    float*        pairr  = (float*)       (ws + WO_PAIRR);
    unsigned int* pairij = (unsigned int*)(ws + WO_PAIRIJ);
    float*        m      = (float*)       (ws + WO_M);
    float*        x      = (float*)       (ws + WO_X);
    float*        xfA    = (float*)       (ws + WO_XF);
    float*        xfB    = (float*)       (ws + WO_XF2);
    float*        epart  = (float*)       (ws + WO_EPART);

    k_detect<<<1, 64, 0, stream>>>(box, flag, pcnt);
    k_build<<<SN_NA, 256, 0, stream>>>(flag, pos, box, pcnt, pairr, pairij);
    k_init<<<SN_NA, SN_F, 0, stream>>>(flag, zn, emb, Win, x, xfA, m);

    float* xf_in = xfA;
    float* xf_out = xfB;
    for (int l = 0; l < 3; l++) {
        k_filter<<<SN_MAXP/SN_BP, 128, 0, stream>>>(flag, pairr, pairij, pcnt,
            Wf1, bf1, Wf2, bf2, xf_in, m, l);
        int layNext = (l < 2) ? (l + 1) : -1;
        k_dense<<<SN_NA/8, 128, 0, stream>>>(flag, m, x,
            W2, b2, W3, b3, Win, l, layNext, xf_out);
        float* t = xf_in; xf_in = xf_out; xf_out = t;
    }

    k_head<<<SN_NA/2, SN_F, 0, stream>>>(flag, x, Wo1, bo1, Wo2, bo2, epart);
    k_reduce<<<1, 256, 0, stream>>>(flag, epart, d_out);
}

// Round 4
// 313.814 us; speedup vs baseline: 1.7906x; 1.7906x over previous
//
#include <hip/hip_runtime.h>

#define SN_NA    800
#define SN_F     128
#define SN_G     50
#define SN_MAXP  16384
#define SN_MAXN  96
#define SN_BP    8
#define SN_CUT2  25.0f

// ---- converted-weight (f32) element offsets inside wt ----
#define OW_WF1 0        // [3][50][128]
#define OW_BF1 19200    // [3][128]
#define OW_WF2 19584    // [3][128][128]
#define OW_BF2 68736    // [3][128]
#define OW_WIN 69120    // [3][128][128]
#define OW_W2  118272   // [3][128][128]
#define OW_B2  167424   // [3][128]
#define OW_W3  167808   // [3][128][128]
#define OW_B3  216960   // [3][128]
#define OW_WO1 217344   // [128][64]
#define OW_BO1 225536   // [64]
#define OW_WO2 225600   // [64]
#define OW_BO2 225664   // [1]
#define NW_TOT 225665

// ---- workspace layout (bytes) ----
#define WO_FLAG   0
#define WO_PCNT   64
#define WO_NCNT   128
#define WO_NBRP   3328
#define WO_NBRO   (WO_NBRP + SN_NA*SN_MAXN*4)
#define WO_PAIRR  (WO_NBRO + SN_NA*SN_MAXN*4)
#define WO_PAIRIJ (WO_PAIRR + SN_MAXP*4)
#define WO_WT     (WO_PAIRIJ + SN_MAXP*4)
#define WO_WPH    ((WO_WT + NW_TOT*4 + 15) & ~15)
#define WO_X      (WO_WPH + SN_MAXP*SN_F*2)
#define WO_XF     (WO_X  + SN_NA*SN_F*4)
#define WO_XF2    (WO_XF + SN_NA*SN_F*4)
#define WO_EPART  (WO_XF2 + SN_NA*SN_F*4)
#define SN_WSNEED (WO_EPART + SN_NA*4)

// scalar dtype-generic load (BF: bf16 bits -> f32)
template <int BF>
__device__ __forceinline__ float ldx(const void* p, int idx) {
    if (BF) {
        unsigned int x = ((unsigned int)(((const unsigned short*)p)[idx])) << 16;
        float f; __builtin_memcpy(&f, &x, 4); return f;
    }
    return ((const float*)p)[idx];
}

__device__ __forceinline__ float bf2f(unsigned short u) {
    unsigned int x = ((unsigned int)u) << 16;
    float f; __builtin_memcpy(&f, &x, 4); return f;
}
__device__ __forceinline__ unsigned short f2bf(float v) {
    unsigned int b; __builtin_memcpy(&b, &v, 4);
    return (unsigned short)((b + 0x7FFFu + ((b >> 16) & 1u)) >> 16);
}

__device__ __forceinline__ float sspf(float v) {
    float sp = fmaxf(v, 0.0f) + log1pf(__expf(-fabsf(v)));
    return sp - 0.69314718055994530942f;
}

// ---------------- dtype detect + counter zeroing ----------------
__global__ void k_detect(const void* box, int* flag, int* pcnt, int* ncnt) {
    int tid = threadIdx.x;
    for (int t = tid; t < SN_NA; t += 256) ncnt[t] = 0;
    if (tid == 0) {
        *pcnt = 0;
        float b0 = ((const float*)box)[0];
        *flag = !(b0 > 1e-3f && b0 < 1e3f);
    }
}

// ---------------- convert all weights to f32 in wt ----------------
__global__ void k_conv(const int* flag, float* wt,
                       const void* wf1, const void* bf1, const void* wf2, const void* bf2,
                       const void* win, const void* w2, const void* b2,
                       const void* w3, const void* b3,
                       const void* wo1, const void* bo1, const void* wo2, const void* bo2) {
    int t = blockIdx.x * 256 + threadIdx.x;
    if (t >= NW_TOT) return;
    const int   sz[13] = {19200,384,49152,384,49152,49152,384,49152,384,8192,64,64,1};
    const void* ps[13] = {wf1,bf1,wf2,bf2,win,w2,b2,w3,b3,wo1,bo1,wo2,bo2};
    int rem = t, s = 0;
#pragma unroll
    for (int q = 0; q < 13; q++) {
        if (rem >= sz[q]) { rem -= sz[q]; s = q + 1; }
        else break;
    }
    float v = (*flag) ? ldx<1>(ps[s], rem) : ldx<0>(ps[s], rem);
    wt[t] = v;
}

// ---------------- pair list + CSR build ----------------
template <int BF>
__device__ void build_body(const void* pos, const void* box,
                           int* pcnt, int* ncnt, int* nbrp, int* nbro,
                           float* pairr, unsigned int* pairij) {
    int i = blockIdx.x;
    float c00 = ldx<BF>(box,0)*10.f, c01 = ldx<BF>(box,1)*10.f, c02 = ldx<BF>(box,2)*10.f;
    float c10 = ldx<BF>(box,3)*10.f, c11 = ldx<BF>(box,4)*10.f, c12 = ldx<BF>(box,5)*10.f;
    float c20 = ldx<BF>(box,6)*10.f, c21 = ldx<BF>(box,7)*10.f, c22 = ldx<BF>(box,8)*10.f;
    float det = c00*(c11*c22 - c12*c21) - c01*(c10*c22 - c12*c20) + c02*(c10*c21 - c11*c20);
    float id  = 1.0f / det;
    float i00 = (c11*c22 - c12*c21)*id, i01 = (c02*c21 - c01*c22)*id, i02 = (c01*c12 - c02*c11)*id;
    float i10 = (c12*c20 - c10*c22)*id, i11 = (c00*c22 - c02*c20)*id, i12 = (c02*c10 - c00*c12)*id;
    float i20 = (c10*c21 - c11*c20)*id, i21 = (c01*c20 - c00*c21)*id, i22 = (c00*c11 - c01*c10)*id;

    float xi = ldx<BF>(pos, i*3+0)*10.f;
    float yi = ldx<BF>(pos, i*3+1)*10.f;
    float zi = ldx<BF>(pos, i*3+2)*10.f;

    for (int j = threadIdx.x; j < SN_NA; j += 256) {
        if (j <= i) continue;
        float dx = xi - ldx<BF>(pos, j*3+0)*10.f;
        float dy = yi - ldx<BF>(pos, j*3+1)*10.f;
        float dz = zi - ldx<BF>(pos, j*3+2)*10.f;
        float fx = dx*i00 + dy*i10 + dz*i20;
        float fy = dx*i01 + dy*i11 + dz*i21;
        float fz = dx*i02 + dy*i12 + dz*i22;
        fx -= rintf(fx); fy -= rintf(fy); fz -= rintf(fz);
        float ax = fx*c00 + fy*c10 + fz*c20;
        float ay = fx*c01 + fy*c11 + fz*c21;
        float az = fx*c02 + fy*c12 + fz*c22;
        float r2 = ax*ax + ay*ay + az*az;
        if (r2 < SN_CUT2) {
            int p = atomicAdd(pcnt, 1);
            if (p < SN_MAXP) {
                pairr[p] = sqrtf(r2);
                pairij[p] = ((unsigned int)i << 16) | (unsigned int)j;
                int ki = atomicAdd(&ncnt[i], 1);
                if (ki < SN_MAXN) { nbrp[i*SN_MAXN+ki] = p; nbro[i*SN_MAXN+ki] = j; }
                int kj = atomicAdd(&ncnt[j], 1);
                if (kj < SN_MAXN) { nbrp[j*SN_MAXN+kj] = p; nbro[j*SN_MAXN+kj] = i; }
            }
        }
    }
}
__global__ void k_build(const int* flag, const void* pos, const void* box,
                        int* pcnt, int* ncnt, int* nbrp, int* nbro,
                        float* pairr, unsigned int* pairij) {
    if (*flag) build_body<1>(pos, box, pcnt, ncnt, nbrp, nbro, pairr, pairij);
    else       build_body<0>(pos, box, pcnt, ncnt, nbrp, nbro, pairr, pairij);
}

// ---------------- x = emb[Z]; xf = x @ Win[0] ----------------
template <int BF>
__device__ void init_body(const int* zn, const void* emb, const float* wt,
                          float* x, float* xf, float* xs) {
    int i = blockIdx.x;
    int f = threadIdx.x;
    float v = ldx<BF>(emb, zn[i]*SN_F + f);
    x[i*SN_F + f] = v;
    xs[f] = v;
    __syncthreads();
    const float* w = wt + OW_WIN;   // layer 0
    float acc = 0.f;
#pragma unroll 4
    for (int k = 0; k < SN_F; k++)
        acc = fmaf(xs[k], w[k*SN_F + f], acc);
    xf[i*SN_F + f] = acc;
}
__global__ void k_init(const int* flag, const int* zn, const void* emb, const float* wt,
                       float* x, float* xf) {
    __shared__ float xs[SN_F];
    if (*flag) init_body<1>(zn, emb, wt, x, xf, xs);
    else       init_body<0>(zn, emb, wt, x, xf, xs);
}

// ---------------- per-pair filter (f32 weights) -> wpair bf16 ----------------
// 8 pairs/block, 128 threads: 16 threads/pair, 8 features/thread.
__global__ void k_filter(const float* pairr, const int* pcnt, const float* wt,
                         unsigned short* wpairh, int lay) {
    __shared__ float gs[SN_BP][52];
    __shared__ float hs[SN_BP][SN_F];
    int cnt = *pcnt; if (cnt > SN_MAXP) cnt = SN_MAXP;
    int p0 = blockIdx.x * SN_BP;
    if (p0 >= cnt) return;
    int tid = threadIdx.x;
    int b  = tid >> 4;
    int f0 = (tid & 15) * 8;
    int p = p0 + b;
    bool live = (p < cnt);

    const float width = 5.0f / 49.0f;
    const float gamma = 0.5f / (width * width);
    for (int t = tid; t < SN_BP*52; t += 128) {
        int bb = t / 52, k = t - bb*52;
        float g = 0.0f;
        int pp = p0 + bb;
        if (k < SN_G && pp < cnt) {
            float d = pairr[pp] - width * (float)k;
            g = __expf(-gamma * d * d);
        }
        gs[bb][k] = g;
    }
    __syncthreads();

    // stage 1: h = ssp(g @ Wf1 + bf1)
    const float* w1 = wt + OW_WF1 + lay*(SN_G*SN_F);
    float acc[8];
#pragma unroll
    for (int q = 0; q < 8; q++) acc[q] = 0.f;
    for (int k = 0; k < SN_G; k++) {
        const float4* wr = (const float4*)(w1 + k*SN_F + f0);
        float4 wa = wr[0], wb = wr[1];
        float g = gs[b][k];
        acc[0] = fmaf(g, wa.x, acc[0]); acc[1] = fmaf(g, wa.y, acc[1]);
        acc[2] = fmaf(g, wa.z, acc[2]); acc[3] = fmaf(g, wa.w, acc[3]);
        acc[4] = fmaf(g, wb.x, acc[4]); acc[5] = fmaf(g, wb.y, acc[5]);
        acc[6] = fmaf(g, wb.z, acc[6]); acc[7] = fmaf(g, wb.w, acc[7]);
    }
    {
        const float* bb1 = wt + OW_BF1 + lay*SN_F + f0;
#pragma unroll
        for (int q = 0; q < 8; q++) hs[b][f0+q] = sspf(acc[q] + bb1[q]);
    }
    __syncthreads();

    // stage 2: W = h @ Wf2 + bf2
    const float* w2 = wt + OW_WF2 + lay*(SN_F*SN_F);
#pragma unroll
    for (int q = 0; q < 8; q++) acc[q] = 0.f;
    for (int k = 0; k < SN_F; k++) {
        const float4* wr = (const float4*)(w2 + k*SN_F + f0);
        float4 wa = wr[0], wb = wr[1];
        float h = hs[b][k];
        acc[0] = fmaf(h, wa.x, acc[0]); acc[1] = fmaf(h, wa.y, acc[1]);
        acc[2] = fmaf(h, wa.z, acc[2]); acc[3] = fmaf(h, wa.w, acc[3]);
        acc[4] = fmaf(h, wb.x, acc[4]); acc[5] = fmaf(h, wb.y, acc[5]);
        acc[6] = fmaf(h, wb.z, acc[6]); acc[7] = fmaf(h, wb.w, acc[7]);
    }
    if (live) {
        const float* bb2 = wt + OW_BF2 + lay*SN_F + f0;
        unsigned short hv[8];
#pragma unroll
        for (int q = 0; q < 8; q++) hv[q] = f2bf(acc[q] + bb2[q]);
        *(uint4*)&wpairh[p*SN_F + f0] = *(uint4*)hv;
    }
}

// ---------------- fused per-atom layer: gather + 3 GEMVs + residual ----------------
// 1 block = 1 atom, 128 threads (thread = feature).
__global__ void k_layer(const int* ncnt, const int* nbrp, const int* nbro,
                        const unsigned short* wpairh, const float* xf_in,
                        float* x, const float* wt, int lay, int layNext,
                        float* xf_out) {
    __shared__ int   sp[SN_MAXN], sj[SN_MAXN];
    __shared__ float sm[SN_F], st[SN_F];
    int i = blockIdx.x;
    int f = threadIdx.x;
    int cn = ncnt[i]; if (cn > SN_MAXN) cn = SN_MAXN;
    if (f < cn) { sp[f] = nbrp[i*SN_MAXN + f]; sj[f] = nbro[i*SN_MAXN + f]; }
    __syncthreads();

    // m[f] = sum_k W_pk[f] * xf[jk][f]   (4-way unrolled, 8 loads in flight)
    float a0 = 0.f, a1 = 0.f, a2 = 0.f, a3 = 0.f;
    int k = 0;
    for (; k + 4 <= cn; k += 4) {
        int p0 = sp[k],   j0 = sj[k];
        int p1 = sp[k+1], j1 = sj[k+1];
        int p2 = sp[k+2], j2 = sj[k+2];
        int p3 = sp[k+3], j3 = sj[k+3];
        float w0 = bf2f(wpairh[p0*SN_F + f]);
        float w1 = bf2f(wpairh[p1*SN_F + f]);
        float w2 = bf2f(wpairh[p2*SN_F + f]);
        float w3 = bf2f(wpairh[p3*SN_F + f]);
        float x0 = xf_in[j0*SN_F + f];
        float x1 = xf_in[j1*SN_F + f];
        float x2 = xf_in[j2*SN_F + f];
        float x3 = xf_in[j3*SN_F + f];
        a0 = fmaf(w0, x0, a0); a1 = fmaf(w1, x1, a1);
        a2 = fmaf(w2, x2, a2); a3 = fmaf(w3, x3, a3);
    }
    for (; k < cn; k++) {
        float w = bf2f(wpairh[sp[k]*SN_F + f]);
        a0 = fmaf(w, xf_in[sj[k]*SN_F + f], a0);
    }
    sm[f] = (a0 + a1) + (a2 + a3);
    __syncthreads();

    // t = ssp(m @ W2 + b2)
    const float* w2p = wt + OW_W2 + lay*(SN_F*SN_F);
    float acc = 0.f;
#pragma unroll 4
    for (int kk = 0; kk < SN_F; kk++)
        acc = fmaf(sm[kk], w2p[kk*SN_F + f], acc);
    st[f] = sspf(acc + wt[OW_B2 + lay*SN_F + f]);
    __syncthreads();

    // v = t @ W3 + b3 ; xnew = x + v
    const float* w3p = wt + OW_W3 + lay*(SN_F*SN_F);
    acc = 0.f;
#pragma unroll 4
    for (int kk = 0; kk < SN_F; kk++)
        acc = fmaf(st[kk], w3p[kk*SN_F + f], acc);
    float xnew = x[i*SN_F + f] + acc + wt[OW_B3 + lay*SN_F + f];
    x[i*SN_F + f] = xnew;

    if (layNext >= 0) {
        __syncthreads();
        sm[f] = xnew;
        __syncthreads();
        const float* wn = wt + OW_WIN + layNext*(SN_F*SN_F);
        acc = 0.f;
#pragma unroll 4
        for (int kk = 0; kk < SN_F; kk++)
            acc = fmaf(sm[kk], wn[kk*SN_F + f], acc);
        xf_out[i*SN_F + f] = acc;
    }
}

// ---------------- energy head ----------------
__global__ void k_head(const float* x, const float* wt, float* epart) {
    __shared__ float xs[2*SN_F];
    int a0 = blockIdx.x * 2;
    int tid = threadIdx.x;
    int a = tid >> 6, fo = tid & 63;
    xs[tid]        = x[a0*SN_F + tid];
    xs[SN_F + tid] = x[(a0+1)*SN_F + tid];
    __syncthreads();
    const float* wo1 = wt + OW_WO1;
    float acc = 0.f;
#pragma unroll 4
    for (int k = 0; k < SN_F; k++)
        acc = fmaf(xs[a*SN_F + k], wo1[k*64 + fo], acc);
    float h = sspf(acc + wt[OW_BO1 + fo]);
    float e = h * wt[OW_WO2 + fo];
#pragma unroll
    for (int off = 32; off > 0; off >>= 1) e += __shfl_down(e, off, 64);
    if (fo == 0) epart[a0 + a] = e + wt[OW_BO2];
}

// ---------------- final reduce + dtype-matched store ----------------
__global__ void k_reduce(const int* flag, const float* epart, void* out) {
    __shared__ float red[256];
    int tid = threadIdx.x;
    float s = 0.f;
    for (int idx = tid; idx < SN_NA; idx += 256) s += epart[idx];
    red[tid] = s;
    __syncthreads();
    for (int w = 128; w > 0; w >>= 1) {
        if (tid < w) red[tid] += red[tid + w];
        __syncthreads();
    }
    if (tid == 0) {
        float v = red[0];
        if (*flag) {
            ((unsigned short*)out)[0] = f2bf(v);
        } else {
            ((float*)out)[0] = v;
        }
    }
}

__global__ void k_fail(void* out) {
    ((unsigned short*)out)[0] = 0x449A;   // bf16 1234.0 sentinel
}

extern "C" void kernel_launch(void* const* d_in, const int* in_sizes, int n_in,
                              void* d_out, int out_size, void* d_ws, size_t ws_size,
                              hipStream_t stream)
{
    const void* pos = d_in[0];
    const void* box = d_in[1];
    const int*  zn  = (const int*)d_in[2];
    const void* emb = d_in[3];

    if (ws_size < (size_t)SN_WSNEED) {
        k_fail<<<1, 1, 0, stream>>>(d_out);
        return;
    }

    char* ws = (char*)d_ws;
    int*            flag   = (int*)           (ws + WO_FLAG);
    int*            pcnt   = (int*)           (ws + WO_PCNT);
    int*            ncnt   = (int*)           (ws + WO_NCNT);
    int*            nbrp   = (int*)           (ws + WO_NBRP);
    int*            nbro   = (int*)           (ws + WO_NBRO);
    float*          pairr  = (float*)         (ws + WO_PAIRR);
    unsigned int*   pairij = (unsigned int*)  (ws + WO_PAIRIJ);
    float*          wt     = (float*)         (ws + WO_WT);
    unsigned short* wpairh = (unsigned short*)(ws + WO_WPH);
    float*          x      = (float*)         (ws + WO_X);
    float*          xfA    = (float*)         (ws + WO_XF);
    float*          xfB    = (float*)         (ws + WO_XF2);
    float*          epart  = (float*)         (ws + WO_EPART);

    k_detect<<<1, 256, 0, stream>>>(box, flag, pcnt, ncnt);
    k_conv<<<(NW_TOT + 255)/256, 256, 0, stream>>>(flag, wt,
        d_in[4], d_in[5], d_in[6], d_in[7], d_in[8], d_in[9], d_in[10],
        d_in[11], d_in[12], d_in[13], d_in[14], d_in[15], d_in[16]);
    k_build<<<SN_NA, 256, 0, stream>>>(flag, pos, box, pcnt, ncnt, nbrp, nbro, pairr, pairij);
    k_init<<<SN_NA, SN_F, 0, stream>>>(flag, zn, emb, wt, x, xfA);

    float* xf_in = xfA;
    float* xf_out = xfB;
    for (int l = 0; l < 3; l++) {
        k_filter<<<SN_MAXP/SN_BP, 128, 0, stream>>>(pairr, pcnt, wt, wpairh, l);
        int layNext = (l < 2) ? (l + 1) : -1;
        k_layer<<<SN_NA, SN_F, 0, stream>>>(ncnt, nbrp, nbro, wpairh, xf_in,
                                            x, wt, l, layNext, xf_out);
        float* t = xf_in; xf_in = xf_out; xf_out = t;
    }

    k_head<<<SN_NA/2, SN_F, 0, stream>>>(x, wt, epart);
    k_reduce<<<1, 256, 0, stream>>>(flag, epart, d_out);
}

// Round 5
// 269.816 us; speedup vs baseline: 2.0826x; 1.1631x over previous
//
#include <hip/hip_runtime.h>

#define SN_NA    800
#define SN_F     128
#define SN_G     50
#define SN_MAXP  16384
#define SN_MAXN  128      // row slots: upper [0,64), lower [64,128)
#define SN_BP    16
#define SN_CUT2  25.0f

// ---- converted-weight (f32) element offsets inside wt ----
#define OW_WF1 0        // [3][50][128]
#define OW_BF1 19200    // [3][128]
#define OW_WF2 19584    // [3][128][128]
#define OW_BF2 68736    // [3][128]
#define OW_WIN 69120    // [3][128][128]
#define OW_W2  118272   // [3][128][128]
#define OW_B2  167424   // [3][128]
#define OW_W3  167808   // [3][128][128]
#define OW_B3  216960   // [3][128]
#define OW_WO1 217344   // [128][64]
#define OW_BO1 225536   // [64]
#define OW_WO2 225600   // [64]
#define OW_BO2 225664   // [1]
#define NW_TOT 225665

// ---- workspace layout (bytes) ----
#define WO_FLAG   0
#define WO_PCNT   64
#define WO_NCUP   128
#define WO_NCLO   (WO_NCUP + SN_NA*4)
#define WO_NBRP   (WO_NCLO + SN_NA*4)
#define WO_NBRO   (WO_NBRP + SN_NA*SN_MAXN*4)
#define WO_PAIRR  (WO_NBRO + SN_NA*SN_MAXN*4)
#define WO_WT     (WO_PAIRR + SN_MAXP*4)
#define WO_WPH    ((WO_WT + NW_TOT*4 + 15) & ~15)
#define WO_X      (WO_WPH + SN_MAXP*SN_F*2)
#define WO_XF     (WO_X  + SN_NA*SN_F*4)
#define WO_XF2    (WO_XF + SN_NA*SN_F*4)
#define WO_EPART  (WO_XF2 + SN_NA*SN_F*4)
#define SN_WSNEED (WO_EPART + SN_NA*4)    // ~7.3 MB (proven ws >= 10.5 MB)

// scalar dtype-generic load (BF: bf16 bits -> f32)
template <int BF>
__device__ __forceinline__ float ldx(const void* p, int idx) {
    if (BF) {
        unsigned int x = ((unsigned int)(((const unsigned short*)p)[idx])) << 16;
        float f; __builtin_memcpy(&f, &x, 4); return f;
    }
    return ((const float*)p)[idx];
}

__device__ __forceinline__ float bf2f(unsigned short u) {
    unsigned int x = ((unsigned int)u) << 16;
    float f; __builtin_memcpy(&f, &x, 4); return f;
}
__device__ __forceinline__ unsigned short f2bf(float v) {
    unsigned int b; __builtin_memcpy(&b, &v, 4);
    return (unsigned short)((b + 0x7FFFu + ((b >> 16) & 1u)) >> 16);
}

__device__ __forceinline__ float sspf(float v) {
    float sp = fmaxf(v, 0.0f) + log1pf(__expf(-fabsf(v)));
    return sp - 0.69314718055994530942f;
}

// ---------------- dtype detect + counter zeroing ----------------
__global__ void k_detect(const void* box, int* flag, int* pcnt, int* nclo) {
    int tid = threadIdx.x;
    for (int t = tid; t < SN_NA; t += 256) nclo[t] = 0;
    if (tid == 0) {
        *pcnt = 0;
        float b0 = ((const float*)box)[0];
        *flag = !(b0 > 1e-3f && b0 < 1e3f);
    }
}

// ---------------- convert all weights to f32 in wt ----------------
__global__ void k_conv(const int* flag, float* wt,
                       const void* wf1, const void* bf1, const void* wf2, const void* bf2,
                       const void* win, const void* w2, const void* b2,
                       const void* w3, const void* b3,
                       const void* wo1, const void* bo1, const void* wo2, const void* bo2) {
    int t = blockIdx.x * 256 + threadIdx.x;
    if (t >= NW_TOT) return;
    const int   sz[13] = {19200,384,49152,384,49152,49152,384,49152,384,8192,64,64,1};
    const void* ps[13] = {wf1,bf1,wf2,bf2,win,w2,b2,w3,b3,wo1,bo1,wo2,bo2};
    int rem = t, s = 0;
#pragma unroll
    for (int q = 0; q < 13; q++) {
        if (rem >= sz[q]) { rem -= sz[q]; s = q + 1; }
        else break;
    }
    float v = (*flag) ? ldx<1>(ps[s], rem) : ldx<0>(ps[s], rem);
    wt[t] = v;
}

// ---------------- pair list + split CSR build (block-aggregated reservation) --
// Block i: finds its upper neighbors (j>i), stages in LDS, reserves a
// contiguous pair range with ONE atomicAdd(pcnt), writes upper CSR slots
// [0,64) deterministically, appends to lower CSR slots [64,128) of row j
// via distributed per-row atomics.
template <int BF>
__device__ void build_body(const void* pos, const void* box,
                           int* pcnt, int* ncup, int* nclo,
                           int* nbrp, int* nbro, float* pairr,
                           int* lj, float* lr, int* lsh) {
    int i = blockIdx.x;
    int tid = threadIdx.x;
    if (tid == 0) lsh[0] = 0;

    float c00 = ldx<BF>(box,0)*10.f, c01 = ldx<BF>(box,1)*10.f, c02 = ldx<BF>(box,2)*10.f;
    float c10 = ldx<BF>(box,3)*10.f, c11 = ldx<BF>(box,4)*10.f, c12 = ldx<BF>(box,5)*10.f;
    float c20 = ldx<BF>(box,6)*10.f, c21 = ldx<BF>(box,7)*10.f, c22 = ldx<BF>(box,8)*10.f;
    float det = c00*(c11*c22 - c12*c21) - c01*(c10*c22 - c12*c20) + c02*(c10*c21 - c11*c20);
    float id  = 1.0f / det;
    float i00 = (c11*c22 - c12*c21)*id, i01 = (c02*c21 - c01*c22)*id, i02 = (c01*c12 - c02*c11)*id;
    float i10 = (c12*c20 - c10*c22)*id, i11 = (c00*c22 - c02*c20)*id, i12 = (c02*c10 - c00*c12)*id;
    float i20 = (c10*c21 - c11*c20)*id, i21 = (c01*c20 - c00*c21)*id, i22 = (c00*c11 - c01*c10)*id;

    float xi = ldx<BF>(pos, i*3+0)*10.f;
    float yi = ldx<BF>(pos, i*3+1)*10.f;
    float zi = ldx<BF>(pos, i*3+2)*10.f;
    __syncthreads();

    for (int j = i + 1 + tid; j < SN_NA; j += 256) {
        float dx = xi - ldx<BF>(pos, j*3+0)*10.f;
        float dy = yi - ldx<BF>(pos, j*3+1)*10.f;
        float dz = zi - ldx<BF>(pos, j*3+2)*10.f;
        float fx = dx*i00 + dy*i10 + dz*i20;
        float fy = dx*i01 + dy*i11 + dz*i21;
        float fz = dx*i02 + dy*i12 + dz*i22;
        fx -= rintf(fx); fy -= rintf(fy); fz -= rintf(fz);
        float ax = fx*c00 + fy*c10 + fz*c20;
        float ay = fx*c01 + fy*c11 + fz*c21;
        float az = fx*c02 + fy*c12 + fz*c22;
        float r2 = ax*ax + ay*ay + az*az;
        if (r2 < SN_CUT2) {
            int k = atomicAdd(&lsh[0], 1);
            if (k < 64) { lj[k] = j; lr[k] = sqrtf(r2); }
        }
    }
    __syncthreads();

    int cnt = lsh[0]; if (cnt > 64) cnt = 64;
    if (tid == 0) lsh[1] = atomicAdd(pcnt, cnt);
    __syncthreads();
    int base = lsh[1];
    int avail = SN_MAXP - base; if (avail < 0) avail = 0;
    int stored = cnt < avail ? cnt : avail;
    if (tid == 0) ncup[i] = stored;

    if (tid < stored) {
        int p = base + tid;
        int j = lj[tid];
        pairr[p] = lr[tid];
        nbrp[i*SN_MAXN + tid] = p;
        nbro[i*SN_MAXN + tid] = j;
        int kj = atomicAdd(&nclo[j], 1);
        if (kj < 64) {
            nbrp[j*SN_MAXN + 64 + kj] = p;
            nbro[j*SN_MAXN + 64 + kj] = i;
        }
    }
}
__global__ void k_build(const int* flag, const void* pos, const void* box,
                        int* pcnt, int* ncup, int* nclo,
                        int* nbrp, int* nbro, float* pairr) {
    __shared__ int   lj[64];
    __shared__ float lr[64];
    __shared__ int   lsh[2];
    if (*flag) build_body<1>(pos, box, pcnt, ncup, nclo, nbrp, nbro, pairr, lj, lr, lsh);
    else       build_body<0>(pos, box, pcnt, ncup, nclo, nbrp, nbro, pairr, lj, lr, lsh);
}

// ---------------- x = emb[Z]; xf = x @ Win[0] ----------------
template <int BF>
__device__ void init_body(const int* zn, const void* emb, const float* wt,
                          float* x, float* xf, float* xs) {
    int i = blockIdx.x;
    int f = threadIdx.x;
    float v = ldx<BF>(emb, zn[i]*SN_F + f);
    x[i*SN_F + f] = v;
    xs[f] = v;
    __syncthreads();
    const float* w = wt + OW_WIN;   // layer 0
    float acc = 0.f;
#pragma unroll 4
    for (int k = 0; k < SN_F; k++)
        acc = fmaf(xs[k], w[k*SN_F + f], acc);
    xf[i*SN_F + f] = acc;
}
__global__ void k_init(const int* flag, const int* zn, const void* emb, const float* wt,
                       float* x, float* xf) {
    __shared__ float xs[SN_F];
    if (*flag) init_body<1>(zn, emb, wt, x, xf, xs);
    else       init_body<0>(zn, emb, wt, x, xf, xs);
}

// ---------------- per-pair filter (f32 weights) -> wpair bf16 ----------------
// 16 pairs/block, 256 threads: 16 threads/pair, 8 features/thread.
__global__ void k_filter(const float* pairr, const int* pcnt, const float* wt,
                         unsigned short* wpairh, int lay) {
    __shared__ float gs[SN_BP][52];
    __shared__ float hs[SN_BP][SN_F];
    int cnt = *pcnt; if (cnt > SN_MAXP) cnt = SN_MAXP;
    int p0 = blockIdx.x * SN_BP;
    if (p0 >= cnt) return;
    int tid = threadIdx.x;
    int b  = tid >> 4;
    int f0 = (tid & 15) * 8;
    int p = p0 + b;
    bool live = (p < cnt);

    const float width = 5.0f / 49.0f;
    const float gamma = 0.5f / (width * width);
    for (int t = tid; t < SN_BP*52; t += 256) {
        int bb = t / 52, k = t - bb*52;
        float g = 0.0f;
        int pp = p0 + bb;
        if (k < SN_G && pp < cnt) {
            float d = pairr[pp] - width * (float)k;
            g = __expf(-gamma * d * d);
        }
        gs[bb][k] = g;
    }
    __syncthreads();

    // stage 1: h = ssp(g @ Wf1 + bf1)
    const float* w1 = wt + OW_WF1 + lay*(SN_G*SN_F);
    float acc[8];
#pragma unroll
    for (int q = 0; q < 8; q++) acc[q] = 0.f;
    for (int k = 0; k < SN_G; k++) {
        const float4* wr = (const float4*)(w1 + k*SN_F + f0);
        float4 wa = wr[0], wb = wr[1];
        float g = gs[b][k];
        acc[0] = fmaf(g, wa.x, acc[0]); acc[1] = fmaf(g, wa.y, acc[1]);
        acc[2] = fmaf(g, wa.z, acc[2]); acc[3] = fmaf(g, wa.w, acc[3]);
        acc[4] = fmaf(g, wb.x, acc[4]); acc[5] = fmaf(g, wb.y, acc[5]);
        acc[6] = fmaf(g, wb.z, acc[6]); acc[7] = fmaf(g, wb.w, acc[7]);
    }
    {
        const float* bb1 = wt + OW_BF1 + lay*SN_F + f0;
#pragma unroll
        for (int q = 0; q < 8; q++) hs[b][f0+q] = sspf(acc[q] + bb1[q]);
    }
    __syncthreads();

    // stage 2: W = h @ Wf2 + bf2
    const float* w2 = wt + OW_WF2 + lay*(SN_F*SN_F);
#pragma unroll
    for (int q = 0; q < 8; q++) acc[q] = 0.f;
    for (int k = 0; k < SN_F; k++) {
        const float4* wr = (const float4*)(w2 + k*SN_F + f0);
        float4 wa = wr[0], wb = wr[1];
        float h = hs[b][k];
        acc[0] = fmaf(h, wa.x, acc[0]); acc[1] = fmaf(h, wa.y, acc[1]);
        acc[2] = fmaf(h, wa.z, acc[2]); acc[3] = fmaf(h, wa.w, acc[3]);
        acc[4] = fmaf(h, wb.x, acc[4]); acc[5] = fmaf(h, wb.y, acc[5]);
        acc[6] = fmaf(h, wb.z, acc[6]); acc[7] = fmaf(h, wb.w, acc[7]);
    }
    if (live) {
        const float* bb2 = wt + OW_BF2 + lay*SN_F + f0;
        unsigned short hv[8];
#pragma unroll
        for (int q = 0; q < 8; q++) hv[q] = f2bf(acc[q] + bb2[q]);
        *(uint4*)&wpairh[p*SN_F + f0] = *(uint4*)hv;
    }
}

// ---------------- fused per-atom layer: gather + 3 GEMVs + residual ----------
// 1 block = 1 atom, 128 threads (thread = feature).
__global__ void k_layer(const int* ncup, const int* nclo,
                        const int* nbrp, const int* nbro,
                        const unsigned short* wpairh, const float* xf_in,
                        float* x, const float* wt, int lay, int layNext,
                        float* xf_out) {
    __shared__ int   sp[SN_MAXN], sj[SN_MAXN];
    __shared__ float sm[SN_F], st[SN_F];
    int i = blockIdx.x;
    int f = threadIdx.x;
    int up = ncup[i]; if (up > 64) up = 64;
    int lo = nclo[i]; if (lo > 64) lo = 64;
    int cn = up + lo;
    if (f < up) { sp[f] = nbrp[i*SN_MAXN + f]; sj[f] = nbro[i*SN_MAXN + f]; }
    if (f >= 64 && f < 64 + lo) {
        int s = up + (f - 64);
        sp[s] = nbrp[i*SN_MAXN + f];
        sj[s] = nbro[i*SN_MAXN + f];
    }
    __syncthreads();

    // m[f] = sum_k W_pk[f] * xf[jk][f]   (4-way unrolled, 8 loads in flight)
    float a0 = 0.f, a1 = 0.f, a2 = 0.f, a3 = 0.f;
    int k = 0;
    for (; k + 4 <= cn; k += 4) {
        int p0 = sp[k],   j0 = sj[k];
        int p1 = sp[k+1], j1 = sj[k+1];
        int p2 = sp[k+2], j2 = sj[k+2];
        int p3 = sp[k+3], j3 = sj[k+3];
        float w0 = bf2f(wpairh[p0*SN_F + f]);
        float w1 = bf2f(wpairh[p1*SN_F + f]);
        float w2 = bf2f(wpairh[p2*SN_F + f]);
        float w3 = bf2f(wpairh[p3*SN_F + f]);
        float x0 = xf_in[j0*SN_F + f];
        float x1 = xf_in[j1*SN_F + f];
        float x2 = xf_in[j2*SN_F + f];
        float x3 = xf_in[j3*SN_F + f];
        a0 = fmaf(w0, x0, a0); a1 = fmaf(w1, x1, a1);
        a2 = fmaf(w2, x2, a2); a3 = fmaf(w3, x3, a3);
    }
    for (; k < cn; k++) {
        float w = bf2f(wpairh[sp[k]*SN_F + f]);
        a0 = fmaf(w, xf_in[sj[k]*SN_F + f], a0);
    }
    sm[f] = (a0 + a1) + (a2 + a3);
    __syncthreads();

    // t = ssp(m @ W2 + b2)
    const float* w2p = wt + OW_W2 + lay*(SN_F*SN_F);
    float acc = 0.f;
#pragma unroll 4
    for (int kk = 0; kk < SN_F; kk++)
        acc = fmaf(sm[kk], w2p[kk*SN_F + f], acc);
    st[f] = sspf(acc + wt[OW_B2 + lay*SN_F + f]);
    __syncthreads();

    // v = t @ W3 + b3 ; xnew = x + v
    const float* w3p = wt + OW_W3 + lay*(SN_F*SN_F);
    acc = 0.f;
#pragma unroll 4
    for (int kk = 0; kk < SN_F; kk++)
        acc = fmaf(st[kk], w3p[kk*SN_F + f], acc);
    float xnew = x[i*SN_F + f] + acc + wt[OW_B3 + lay*SN_F + f];
    x[i*SN_F + f] = xnew;

    if (layNext >= 0) {
        __syncthreads();
        sm[f] = xnew;
        __syncthreads();
        const float* wn = wt + OW_WIN + layNext*(SN_F*SN_F);
        acc = 0.f;
#pragma unroll 4
        for (int kk = 0; kk < SN_F; kk++)
            acc = fmaf(sm[kk], wn[kk*SN_F + f], acc);
        xf_out[i*SN_F + f] = acc;
    }
}

// ---------------- energy head ----------------
__global__ void k_head(const float* x, const float* wt, float* epart) {
    __shared__ float xs[2*SN_F];
    int a0 = blockIdx.x * 2;
    int tid = threadIdx.x;
    int a = tid >> 6, fo = tid & 63;
    xs[tid]        = x[a0*SN_F + tid];
    xs[SN_F + tid] = x[(a0+1)*SN_F + tid];
    __syncthreads();
    const float* wo1 = wt + OW_WO1;
    float acc = 0.f;
#pragma unroll 4
    for (int k = 0; k < SN_F; k++)
        acc = fmaf(xs[a*SN_F + k], wo1[k*64 + fo], acc);
    float h = sspf(acc + wt[OW_BO1 + fo]);
    float e = h * wt[OW_WO2 + fo];
#pragma unroll
    for (int off = 32; off > 0; off >>= 1) e += __shfl_down(e, off, 64);
    if (fo == 0) epart[a0 + a] = e + wt[OW_BO2];
}

// ---------------- final reduce + dtype-matched store ----------------
__global__ void k_reduce(const int* flag, const float* epart, void* out) {
    __shared__ float red[256];
    int tid = threadIdx.x;
    float s = 0.f;
    for (int idx = tid; idx < SN_NA; idx += 256) s += epart[idx];
    red[tid] = s;
    __syncthreads();
    for (int w = 128; w > 0; w >>= 1) {
        if (tid < w) red[tid] += red[tid + w];
        __syncthreads();
    }
    if (tid == 0) {
        float v = red[0];
        if (*flag) {
            ((unsigned short*)out)[0] = f2bf(v);
        } else {
            ((float*)out)[0] = v;
        }
    }
}

__global__ void k_fail(void* out) {
    ((unsigned short*)out)[0] = 0x449A;   // bf16 1234.0 sentinel
}

extern "C" void kernel_launch(void* const* d_in, const int* in_sizes, int n_in,
                              void* d_out, int out_size, void* d_ws, size_t ws_size,
                              hipStream_t stream)
{
    const void* pos = d_in[0];
    const void* box = d_in[1];
    const int*  zn  = (const int*)d_in[2];
    const void* emb = d_in[3];

    if (ws_size < (size_t)SN_WSNEED) {
        k_fail<<<1, 1, 0, stream>>>(d_out);
        return;
    }

    char* ws = (char*)d_ws;
    int*            flag   = (int*)           (ws + WO_FLAG);
    int*            pcnt   = (int*)           (ws + WO_PCNT);
    int*            ncup   = (int*)           (ws + WO_NCUP);
    int*            nclo   = (int*)           (ws + WO_NCLO);
    int*            nbrp   = (int*)           (ws + WO_NBRP);
    int*            nbro   = (int*)           (ws + WO_NBRO);
    float*          pairr  = (float*)         (ws + WO_PAIRR);
    float*          wt     = (float*)         (ws + WO_WT);
    unsigned short* wpairh = (unsigned short*)(ws + WO_WPH);
    float*          x      = (float*)         (ws + WO_X);
    float*          xfA    = (float*)         (ws + WO_XF);
    float*          xfB    = (float*)         (ws + WO_XF2);
    float*          epart  = (float*)         (ws + WO_EPART);

    k_detect<<<1, 256, 0, stream>>>(box, flag, pcnt, nclo);
    k_conv<<<(NW_TOT + 255)/256, 256, 0, stream>>>(flag, wt,
        d_in[4], d_in[5], d_in[6], d_in[7], d_in[8], d_in[9], d_in[10],
        d_in[11], d_in[12], d_in[13], d_in[14], d_in[15], d_in[16]);
    k_build<<<SN_NA, 256, 0, stream>>>(flag, pos, box, pcnt, ncup, nclo,
                                       nbrp, nbro, pairr);
    k_init<<<SN_NA, SN_F, 0, stream>>>(flag, zn, emb, wt, x, xfA);

    float* xf_in = xfA;
    float* xf_out = xfB;
    for (int l = 0; l < 3; l++) {
        k_filter<<<SN_MAXP/SN_BP, 256, 0, stream>>>(pairr, pcnt, wt, wpairh, l);
        int layNext = (l < 2) ? (l + 1) : -1;
        k_layer<<<SN_NA, SN_F, 0, stream>>>(ncup, nclo, nbrp, nbro, wpairh, xf_in,
                                            x, wt, l, layNext, xf_out);
        float* t = xf_in; xf_in = xf_out; xf_out = t;
    }

    k_head<<<SN_NA/2, SN_F, 0, stream>>>(x, wt, epart);
    k_reduce<<<1, 256, 0, stream>>>(flag, epart, d_out);
}

// Round 6
// 172.642 us; speedup vs baseline: 3.2549x; 1.5629x over previous
//
#include <hip/hip_runtime.h>

#define SN_NA    800
#define SN_F     128
#define SN_G     50
#define SN_MAXP  16384
#define SN_MAXN  128      // row slots: upper [0,64), lower [64,128)
#define SN_CUT2  25.0f

typedef __attribute__((ext_vector_type(4))) float f32x4;
typedef __attribute__((ext_vector_type(8))) short short8;

// ---- converted-weight (f32) element offsets inside wt ----
#define OW_WF1 0        // [3][50][128]
#define OW_BF1 19200    // [3][128]
#define OW_WF2 19584    // [3][128][128]
#define OW_BF2 68736    // [3][128]
#define OW_WIN 69120    // [3][128][128]
#define OW_W2  118272   // [3][128][128]
#define OW_B2  167424   // [3][128]
#define OW_W3  167808   // [3][128][128]
#define OW_B3  216960   // [3][128]
#define OW_WO1 217344   // [128][64]
#define OW_BO1 225536   // [64]
#define OW_WO2 225600   // [64]
#define OW_BO2 225664   // [1]
#define NW_TOT 225665

// ---- transposed bf16 weights (element offsets inside wtT) ----
#define OT_WF1T 0                  // [3][128 col][64 k]  (k>=50 zero)
#define OT_WF2T 24576              // [3][128 col][128 k]
#define NT_TOT  73728

// ---- workspace layout (bytes) ----
#define WO_FLAG   0
#define WO_PCNT   64
#define WO_NCUP   128
#define WO_NCLO   (WO_NCUP + SN_NA*4)
#define WO_NBRP   (WO_NCLO + SN_NA*4)
#define WO_NBRO   (WO_NBRP + SN_NA*SN_MAXN*4)
#define WO_PAIRR  (WO_NBRO + SN_NA*SN_MAXN*4)
#define WO_WT     (WO_PAIRR + SN_MAXP*4)
#define WO_WTT    ((WO_WT + NW_TOT*4 + 15) & ~15)
#define WO_WPH    ((WO_WTT + NT_TOT*2 + 15) & ~15)
#define WO_X      (WO_WPH + SN_MAXP*SN_F*2)
#define WO_XF     (WO_X  + SN_NA*SN_F*4)
#define WO_XF2    (WO_XF + SN_NA*SN_F*4)
#define WO_EPART  (WO_XF2 + SN_NA*SN_F*4)
#define SN_WSNEED (WO_EPART + SN_NA*4)

// scalar dtype-generic load (BF: bf16 bits -> f32)
template <int BF>
__device__ __forceinline__ float ldx(const void* p, int idx) {
    if (BF) {
        unsigned int x = ((unsigned int)(((const unsigned short*)p)[idx])) << 16;
        float f; __builtin_memcpy(&f, &x, 4); return f;
    }
    return ((const float*)p)[idx];
}

__device__ __forceinline__ float bf2f(unsigned short u) {
    unsigned int x = ((unsigned int)u) << 16;
    float f; __builtin_memcpy(&f, &x, 4); return f;
}
__device__ __forceinline__ unsigned short f2bf(float v) {
    unsigned int b; __builtin_memcpy(&b, &v, 4);
    return (unsigned short)((b + 0x7FFFu + ((b >> 16) & 1u)) >> 16);
}

__device__ __forceinline__ float sspf(float v) {
    float sp = fmaxf(v, 0.0f) + log1pf(__expf(-fabsf(v)));
    return sp - 0.69314718055994530942f;
}

// ---------------- dtype detect + counter zeroing ----------------
__global__ void k_detect(const void* box, int* flag, int* pcnt, int* nclo) {
    int tid = threadIdx.x;
    for (int t = tid; t < SN_NA; t += 256) nclo[t] = 0;
    if (tid == 0) {
        *pcnt = 0;
        float b0 = ((const float*)box)[0];
        *flag = !(b0 > 1e-3f && b0 < 1e3f);
    }
}

// ---------------- convert all weights to f32 in wt ----------------
__global__ void k_conv(const int* flag, float* wt,
                       const void* wf1, const void* bf1, const void* wf2, const void* bf2,
                       const void* win, const void* w2, const void* b2,
                       const void* w3, const void* b3,
                       const void* wo1, const void* bo1, const void* wo2, const void* bo2) {
    int t = blockIdx.x * 256 + threadIdx.x;
    if (t >= NW_TOT) return;
    const int   sz[13] = {19200,384,49152,384,49152,49152,384,49152,384,8192,64,64,1};
    const void* ps[13] = {wf1,bf1,wf2,bf2,win,w2,b2,w3,b3,wo1,bo1,wo2,bo2};
    int rem = t, s = 0;
#pragma unroll
    for (int q = 0; q < 13; q++) {
        if (rem >= sz[q]) { rem -= sz[q]; s = q + 1; }
        else break;
    }
    float v = (*flag) ? ldx<1>(ps[s], rem) : ldx<0>(ps[s], rem);
    wt[t] = v;
}

// ---------------- transposed bf16 filter weights ----------------
// wf1T[lay][col][k] = Wf1[lay][k][col] (k<50, else 0); wf2T[lay][col][k] = Wf2[lay][k][col]
__global__ void k_convT(const int* flag, unsigned short* wtT,
                        const void* wf1, const void* wf2) {
    int t = blockIdx.x * 256 + threadIdx.x;
    if (t >= NT_TOT) return;
    float v;
    if (t < OT_WF2T) {
        int lay = t / 8192, rem = t - lay*8192;
        int col = rem >> 6, k = rem & 63;
        v = (k < SN_G) ? ((*flag) ? ldx<1>(wf1, lay*SN_G*SN_F + k*SN_F + col)
                                  : ldx<0>(wf1, lay*SN_G*SN_F + k*SN_F + col))
                       : 0.0f;
    } else {
        int t2 = t - OT_WF2T;
        int lay = t2 / 16384, rem = t2 - lay*16384;
        int col = rem >> 7, k = rem & 127;
        v = (*flag) ? ldx<1>(wf2, lay*SN_F*SN_F + k*SN_F + col)
                    : ldx<0>(wf2, lay*SN_F*SN_F + k*SN_F + col);
    }
    wtT[t] = f2bf(v);
}

// ---------------- pair list + split CSR build (block-aggregated) ----------------
template <int BF>
__device__ void build_body(const void* pos, const void* box,
                           int* pcnt, int* ncup, int* nclo,
                           int* nbrp, int* nbro, float* pairr,
                           int* lj, float* lr, int* lsh) {
    int i = blockIdx.x;
    int tid = threadIdx.x;
    if (tid == 0) lsh[0] = 0;

    float c00 = ldx<BF>(box,0)*10.f, c01 = ldx<BF>(box,1)*10.f, c02 = ldx<BF>(box,2)*10.f;
    float c10 = ldx<BF>(box,3)*10.f, c11 = ldx<BF>(box,4)*10.f, c12 = ldx<BF>(box,5)*10.f;
    float c20 = ldx<BF>(box,6)*10.f, c21 = ldx<BF>(box,7)*10.f, c22 = ldx<BF>(box,8)*10.f;
    float det = c00*(c11*c22 - c12*c21) - c01*(c10*c22 - c12*c20) + c02*(c10*c21 - c11*c20);
    float id  = 1.0f / det;
    float i00 = (c11*c22 - c12*c21)*id, i01 = (c02*c21 - c01*c22)*id, i02 = (c01*c12 - c02*c11)*id;
    float i10 = (c12*c20 - c10*c22)*id, i11 = (c00*c22 - c02*c20)*id, i12 = (c02*c10 - c00*c12)*id;
    float i20 = (c10*c21 - c11*c20)*id, i21 = (c01*c20 - c00*c21)*id, i22 = (c00*c11 - c01*c10)*id;

    float xi = ldx<BF>(pos, i*3+0)*10.f;
    float yi = ldx<BF>(pos, i*3+1)*10.f;
    float zi = ldx<BF>(pos, i*3+2)*10.f;
    __syncthreads();

    for (int j = i + 1 + tid; j < SN_NA; j += 256) {
        float dx = xi - ldx<BF>(pos, j*3+0)*10.f;
        float dy = yi - ldx<BF>(pos, j*3+1)*10.f;
        float dz = zi - ldx<BF>(pos, j*3+2)*10.f;
        float fx = dx*i00 + dy*i10 + dz*i20;
        float fy = dx*i01 + dy*i11 + dz*i21;
        float fz = dx*i02 + dy*i12 + dz*i22;
        fx -= rintf(fx); fy -= rintf(fy); fz -= rintf(fz);
        float ax = fx*c00 + fy*c10 + fz*c20;
        float ay = fx*c01 + fy*c11 + fz*c21;
        float az = fx*c02 + fy*c12 + fz*c22;
        float r2 = ax*ax + ay*ay + az*az;
        if (r2 < SN_CUT2) {
            int k = atomicAdd(&lsh[0], 1);
            if (k < 64) { lj[k] = j; lr[k] = sqrtf(r2); }
        }
    }
    __syncthreads();

    int cnt = lsh[0]; if (cnt > 64) cnt = 64;
    if (tid == 0) lsh[1] = atomicAdd(pcnt, cnt);
    __syncthreads();
    int base = lsh[1];
    int avail = SN_MAXP - base; if (avail < 0) avail = 0;
    int stored = cnt < avail ? cnt : avail;
    if (tid == 0) ncup[i] = stored;

    if (tid < stored) {
        int p = base + tid;
        int j = lj[tid];
        pairr[p] = lr[tid];
        nbrp[i*SN_MAXN + tid] = p;
        nbro[i*SN_MAXN + tid] = j;
        int kj = atomicAdd(&nclo[j], 1);
        if (kj < 64) {
            nbrp[j*SN_MAXN + 64 + kj] = p;
            nbro[j*SN_MAXN + 64 + kj] = i;
        }
    }
}
__global__ void k_build(const int* flag, const void* pos, const void* box,
                        int* pcnt, int* ncup, int* nclo,
                        int* nbrp, int* nbro, float* pairr) {
    __shared__ int   lj[64];
    __shared__ float lr[64];
    __shared__ int   lsh[2];
    if (*flag) build_body<1>(pos, box, pcnt, ncup, nclo, nbrp, nbro, pairr, lj, lr, lsh);
    else       build_body<0>(pos, box, pcnt, ncup, nclo, nbrp, nbro, pairr, lj, lr, lsh);
}

// ---------------- x = emb[Z]; xf = x @ Win[0] ----------------
template <int BF>
__device__ void init_body(const int* zn, const void* emb, const float* wt,
                          float* x, float* xf, float* xs) {
    int i = blockIdx.x;
    int f = threadIdx.x;
    float v = ldx<BF>(emb, zn[i]*SN_F + f);
    x[i*SN_F + f] = v;
    xs[f] = v;
    __syncthreads();
    const float* w = wt + OW_WIN;   // layer 0
    float acc = 0.f;
#pragma unroll 4
    for (int k = 0; k < SN_F; k++)
        acc = fmaf(xs[k], w[k*SN_F + f], acc);
    xf[i*SN_F + f] = acc;
}
__global__ void k_init(const int* flag, const int* zn, const void* emb, const float* wt,
                       float* x, float* xf) {
    __shared__ float xs[SN_F];
    if (*flag) init_body<1>(zn, emb, wt, x, xf, xs);
    else       init_body<0>(zn, emb, wt, x, xf, xs);
}

// ---------------- MFMA per-pair filter ----------------
// Block = 16 pairs, 256 threads = 4 waves; wave w owns output cols [w*32, w*32+32).
// Stage 1: H[16][128] = ssp(G[16][64] @ Wf1T^T + bf1)   (2 K-steps x 2 col-tiles)
// Stage 2: Wij[16][128] = H @ Wf2T^T + bf2              (4 K-steps x 2 col-tiles)
// A-frag: row=lane&15, k=(lane>>4)*8+e ; B-frag: col=lane&15, k=(lane>>4)*8+e
// C-frag: col=lane&15, row=(lane>>4)*4+reg   [m89-verified]
__global__ void k_filter(const float* pairr, const int* pcnt,
                         const float* wt, const unsigned short* wtT,
                         unsigned short* wpairh, int lay) {
    __shared__ unsigned short gls[16][72];    // 144B row stride (16B-aligned, 2-way banks)
    __shared__ unsigned short hls[16][136];   // 272B row stride (16B-aligned, 2-way banks)
    int cnt = *pcnt; if (cnt > SN_MAXP) cnt = SN_MAXP;
    int p0 = blockIdx.x * 16;
    if (p0 >= cnt) return;
    int tid  = threadIdx.x;
    int lane = tid & 63;
    int wave = tid >> 6;
    int c0   = wave * 32;

    // ---- G tile: g[pair][k] = exp(-gamma (r - width k)^2), k<50 ----
    {
        int pr = tid >> 4, k0 = (tid & 15) * 4;
        int p = p0 + pr;
        float r = (p < cnt) ? pairr[p] : -1.0f;
        const float width = 5.0f/49.0f, gamma = 0.5f/(width*width);
        unsigned short gv[4];
#pragma unroll
        for (int q = 0; q < 4; q++) {
            int k = k0 + q;
            float g = 0.f;
            if (k < SN_G && r >= 0.f) { float d = r - width*(float)k; g = __expf(-gamma*d*d); }
            gv[q] = f2bf(g);
        }
        *(unsigned long long*)&gls[pr][k0] = *(unsigned long long*)gv;
    }
    __syncthreads();

    int rowA = lane & 15;
    int kgrp = lane >> 4;

    // ---- stage 1 ----
    f32x4 acc0 = {0.f,0.f,0.f,0.f}, acc1 = {0.f,0.f,0.f,0.f};
    const unsigned short* b1 = wtT + OT_WF1T + lay*8192;
#pragma unroll
    for (int ks = 0; ks < 2; ks++) {
        short8 a  = *(const short8*)&gls[rowA][ks*32 + kgrp*8];
        short8 w0 = *(const short8*)(b1 + (c0 + rowA)*64      + ks*32 + kgrp*8);
        short8 w1 = *(const short8*)(b1 + (c0 + 16 + rowA)*64 + ks*32 + kgrp*8);
        acc0 = __builtin_amdgcn_mfma_f32_16x16x32_bf16(a, w0, acc0, 0, 0, 0);
        acc1 = __builtin_amdgcn_mfma_f32_16x16x32_bf16(a, w1, acc1, 0, 0, 0);
    }
    {
        float b1c0 = wt[OW_BF1 + lay*SN_F + c0 + rowA];
        float b1c1 = wt[OW_BF1 + lay*SN_F + c0 + 16 + rowA];
        int rbase = kgrp * 4;
#pragma unroll
        for (int r = 0; r < 4; r++) {
            hls[rbase + r][c0 + rowA]      = f2bf(sspf(acc0[r] + b1c0));
            hls[rbase + r][c0 + 16 + rowA] = f2bf(sspf(acc1[r] + b1c1));
        }
    }
    __syncthreads();

    // ---- stage 2 ----
    f32x4 d0 = {0.f,0.f,0.f,0.f}, d1 = {0.f,0.f,0.f,0.f};
    const unsigned short* b2 = wtT + OT_WF2T + lay*16384;
#pragma unroll
    for (int ks = 0; ks < 4; ks++) {
        short8 a  = *(const short8*)&hls[rowA][ks*32 + kgrp*8];
        short8 w0 = *(const short8*)(b2 + (c0 + rowA)*128      + ks*32 + kgrp*8);
        short8 w1 = *(const short8*)(b2 + (c0 + 16 + rowA)*128 + ks*32 + kgrp*8);
        d0 = __builtin_amdgcn_mfma_f32_16x16x32_bf16(a, w0, d0, 0, 0, 0);
        d1 = __builtin_amdgcn_mfma_f32_16x16x32_bf16(a, w1, d1, 0, 0, 0);
    }
    {
        float b2c0 = wt[OW_BF2 + lay*SN_F + c0 + rowA];
        float b2c1 = wt[OW_BF2 + lay*SN_F + c0 + 16 + rowA];
        int rbase = kgrp * 4;
#pragma unroll
        for (int r = 0; r < 4; r++) {
            int p = p0 + rbase + r;   // pad rows written but never referenced by CSR
            wpairh[p*SN_F + c0 + rowA]      = f2bf(d0[r] + b2c0);
            wpairh[p*SN_F + c0 + 16 + rowA] = f2bf(d1[r] + b2c1);
        }
    }
}

// ---------------- fused per-atom layer: gather + 3 GEMVs + residual ----------
__global__ void k_layer(const int* ncup, const int* nclo,
                        const int* nbrp, const int* nbro,
                        const unsigned short* wpairh, const float* xf_in,
                        float* x, const float* wt, int lay, int layNext,
                        float* xf_out) {
    __shared__ int   sp[SN_MAXN], sj[SN_MAXN];
    __shared__ float sm[SN_F], st[SN_F];
    int i = blockIdx.x;
    int f = threadIdx.x;
    int up = ncup[i]; if (up > 64) up = 64;
    int lo = nclo[i]; if (lo > 64) lo = 64;
    int cn = up + lo;
    if (f < up) { sp[f] = nbrp[i*SN_MAXN + f]; sj[f] = nbro[i*SN_MAXN + f]; }
    if (f >= 64 && f < 64 + lo) {
        int s = up + (f - 64);
        sp[s] = nbrp[i*SN_MAXN + f];
        sj[s] = nbro[i*SN_MAXN + f];
    }
    __syncthreads();

    float a0 = 0.f, a1 = 0.f, a2 = 0.f, a3 = 0.f;
    int k = 0;
    for (; k + 4 <= cn; k += 4) {
        int p0 = sp[k],   j0 = sj[k];
        int p1 = sp[k+1], j1 = sj[k+1];
        int p2 = sp[k+2], j2 = sj[k+2];
        int p3 = sp[k+3], j3 = sj[k+3];
        float w0 = bf2f(wpairh[p0*SN_F + f]);
        float w1 = bf2f(wpairh[p1*SN_F + f]);
        float w2 = bf2f(wpairh[p2*SN_F + f]);
        float w3 = bf2f(wpairh[p3*SN_F + f]);
        float x0 = xf_in[j0*SN_F + f];
        float x1 = xf_in[j1*SN_F + f];
        float x2 = xf_in[j2*SN_F + f];
        float x3 = xf_in[j3*SN_F + f];
        a0 = fmaf(w0, x0, a0); a1 = fmaf(w1, x1, a1);
        a2 = fmaf(w2, x2, a2); a3 = fmaf(w3, x3, a3);
    }
    for (; k < cn; k++) {
        float w = bf2f(wpairh[sp[k]*SN_F + f]);
        a0 = fmaf(w, xf_in[sj[k]*SN_F + f], a0);
    }
    sm[f] = (a0 + a1) + (a2 + a3);
    __syncthreads();

    const float* w2p = wt + OW_W2 + lay*(SN_F*SN_F);
    float acc = 0.f;
#pragma unroll 4
    for (int kk = 0; kk < SN_F; kk++)
        acc = fmaf(sm[kk], w2p[kk*SN_F + f], acc);
    st[f] = sspf(acc + wt[OW_B2 + lay*SN_F + f]);
    __syncthreads();

    const float* w3p = wt + OW_W3 + lay*(SN_F*SN_F);
    acc = 0.f;
#pragma unroll 4
    for (int kk = 0; kk < SN_F; kk++)
        acc = fmaf(st[kk], w3p[kk*SN_F + f], acc);
    float xnew = x[i*SN_F + f] + acc + wt[OW_B3 + lay*SN_F + f];
    x[i*SN_F + f] = xnew;

    if (layNext >= 0) {
        __syncthreads();
        sm[f] = xnew;
        __syncthreads();
        const float* wn = wt + OW_WIN + layNext*(SN_F*SN_F);
        acc = 0.f;
#pragma unroll 4
        for (int kk = 0; kk < SN_F; kk++)
            acc = fmaf(sm[kk], wn[kk*SN_F + f], acc);
        xf_out[i*SN_F + f] = acc;
    }
}

// ---------------- energy head ----------------
__global__ void k_head(const float* x, const float* wt, float* epart) {
    __shared__ float xs[2*SN_F];
    int a0 = blockIdx.x * 2;
    int tid = threadIdx.x;
    int a = tid >> 6, fo = tid & 63;
    xs[tid]        = x[a0*SN_F + tid];
    xs[SN_F + tid] = x[(a0+1)*SN_F + tid];
    __syncthreads();
    const float* wo1 = wt + OW_WO1;
    float acc = 0.f;
#pragma unroll 4
    for (int k = 0; k < SN_F; k++)
        acc = fmaf(xs[a*SN_F + k], wo1[k*64 + fo], acc);
    float h = sspf(acc + wt[OW_BO1 + fo]);
    float e = h * wt[OW_WO2 + fo];
#pragma unroll
    for (int off = 32; off > 0; off >>= 1) e += __shfl_down(e, off, 64);
    if (fo == 0) epart[a0 + a] = e + wt[OW_BO2];
}

// ---------------- final reduce + dtype-matched store ----------------
__global__ void k_reduce(const int* flag, const float* epart, void* out) {
    __shared__ float red[256];
    int tid = threadIdx.x;
    float s = 0.f;
    for (int idx = tid; idx < SN_NA; idx += 256) s += epart[idx];
    red[tid] = s;
    __syncthreads();
    for (int w = 128; w > 0; w >>= 1) {
        if (tid < w) red[tid] += red[tid + w];
        __syncthreads();
    }
    if (tid == 0) {
        float v = red[0];
        if (*flag) {
            ((unsigned short*)out)[0] = f2bf(v);
        } else {
            ((float*)out)[0] = v;
        }
    }
}

__global__ void k_fail(void* out) {
    ((unsigned short*)out)[0] = 0x449A;   // bf16 1234.0 sentinel
}

extern "C" void kernel_launch(void* const* d_in, const int* in_sizes, int n_in,
                              void* d_out, int out_size, void* d_ws, size_t ws_size,
                              hipStream_t stream)
{
    const void* pos = d_in[0];
    const void* box = d_in[1];
    const int*  zn  = (const int*)d_in[2];
    const void* emb = d_in[3];

    if (ws_size < (size_t)SN_WSNEED) {
        k_fail<<<1, 1, 0, stream>>>(d_out);
        return;
    }

    char* ws = (char*)d_ws;
    int*            flag   = (int*)           (ws + WO_FLAG);
    int*            pcnt   = (int*)           (ws + WO_PCNT);
    int*            ncup   = (int*)           (ws + WO_NCUP);
    int*            nclo   = (int*)           (ws + WO_NCLO);
    int*            nbrp   = (int*)           (ws + WO_NBRP);
    int*            nbro   = (int*)           (ws + WO_NBRO);
    float*          pairr  = (float*)         (ws + WO_PAIRR);
    float*          wt     = (float*)         (ws + WO_WT);
    unsigned short* wtT    = (unsigned short*)(ws + WO_WTT);
    unsigned short* wpairh = (unsigned short*)(ws + WO_WPH);
    float*          x      = (float*)         (ws + WO_X);
    float*          xfA    = (float*)         (ws + WO_XF);
    float*          xfB    = (float*)         (ws + WO_XF2);
    float*          epart  = (float*)         (ws + WO_EPART);

    k_detect<<<1, 256, 0, stream>>>(box, flag, pcnt, nclo);
    k_conv<<<(NW_TOT + 255)/256, 256, 0, stream>>>(flag, wt,
        d_in[4], d_in[5], d_in[6], d_in[7], d_in[8], d_in[9], d_in[10],
        d_in[11], d_in[12], d_in[13], d_in[14], d_in[15], d_in[16]);
    k_convT<<<(NT_TOT + 255)/256, 256, 0, stream>>>(flag, wtT, d_in[4], d_in[6]);
    k_build<<<SN_NA, 256, 0, stream>>>(flag, pos, box, pcnt, ncup, nclo,
                                       nbrp, nbro, pairr);
    k_init<<<SN_NA, SN_F, 0, stream>>>(flag, zn, emb, wt, x, xfA);

    float* xf_in = xfA;
    float* xf_out = xfB;
    for (int l = 0; l < 3; l++) {
        k_filter<<<SN_MAXP/16, 256, 0, stream>>>(pairr, pcnt, wt, wtT, wpairh, l);
        int layNext = (l < 2) ? (l + 1) : -1;
        k_layer<<<SN_NA, SN_F, 0, stream>>>(ncup, nclo, nbrp, nbro, wpairh, xf_in,
                                            x, wt, l, layNext, xf_out);
        float* t = xf_in; xf_in = xf_out; xf_out = t;
    }

    k_head<<<SN_NA/2, SN_F, 0, stream>>>(x, wt, epart);
    k_reduce<<<1, 256, 0, stream>>>(flag, epart, d_out);
}

// Round 7
// 139.430 us; speedup vs baseline: 4.0302x; 1.2382x over previous
//
#include <hip/hip_runtime.h>

#define SN_NA    800
#define SN_F     128
#define SN_G     50
#define SN_MAXP  16384
#define SN_MAXN  128      // row slots: upper [0,64), lower [64,128)
#define SN_CUT2  25.0f

typedef __attribute__((ext_vector_type(4))) float f32x4;
typedef __attribute__((ext_vector_type(8))) short short8;

// ---- f32 bias offsets (elements, inside wb) ----
#define OB_BF1 0        // [3][128]
#define OB_BF2 384
#define OB_B2  768
#define OB_B3  1152
#define OB_BO1 1536     // [64]
#define OB_WO2 1600     // [64]
#define OB_BO2 1664     // [1]
#define NB_TOT 1665

// ---- bf16 transposed weights (elements, inside wtT): wT[col][k] = W[k][col] ----
#define OT_WF1T 0        // [3][128][64] (k>=50 zero)
#define OT_WF2T 24576    // [3][128][128]
#define OT_W2T  73728    // [3][128][128]
#define OT_W3T  122880   // [3][128][128]
#define OT_WINT 172032   // [3][128][128]
#define OT_WO1T 221184   // [64][128]
#define NT_TOT  229376

// ---- ws layout (bytes) ----
#define WO_PCNT  0
#define WO_NCUP  64
#define WO_NCLO  3264
#define WO_NBRP  6464
#define WO_NBRO  (WO_NBRP + SN_NA*SN_MAXN*4)
#define WO_PAIRR (WO_NBRO + SN_NA*SN_MAXN*4)
#define WO_WB    (WO_PAIRR + SN_MAXP*4)
#define WO_WTT   ((WO_WB + NB_TOT*4 + 15) & ~15)
#define WO_WPH   ((WO_WTT + NT_TOT*2 + 15) & ~15)
#define WO_X     (WO_WPH + 3*SN_MAXP*SN_F*2)
#define WO_XF    (WO_X  + SN_NA*SN_F*4)
#define WO_XF2   (WO_XF + SN_NA*SN_F*4)
#define WO_XH    (WO_XF2 + SN_NA*SN_F*4)
#define SN_WSNEED (WO_XH + SN_NA*SN_F*2)   // ~15.4 MB

// runtime dtype-generic scalar load
__device__ __forceinline__ float ldr(const void* p, int idx, int bf) {
    if (bf) {
        unsigned int x = ((unsigned int)(((const unsigned short*)p)[idx])) << 16;
        float f; __builtin_memcpy(&f, &x, 4); return f;
    }
    return ((const float*)p)[idx];
}
__device__ __forceinline__ int bfflag(const void* box) {
    float b0 = ((const float*)box)[0];    // f32: ~2.3 ; bf16 pair reinterpreted: denormal
    return !(b0 > 1e-3f && b0 < 1e3f);
}
__device__ __forceinline__ float bf2f(unsigned short u) {
    unsigned int x = ((unsigned int)u) << 16;
    float f; __builtin_memcpy(&f, &x, 4); return f;
}
__device__ __forceinline__ unsigned short f2bf(float v) {
    unsigned int b; __builtin_memcpy(&b, &v, 4);
    return (unsigned short)((b + 0x7FFFu + ((b >> 16) & 1u)) >> 16);
}
__device__ __forceinline__ float sspf(float v) {
    float sp = fmaxf(v, 0.0f) + log1pf(__expf(-fabsf(v)));
    return sp - 0.69314718055994530942f;
}

// ---------------- setup: zero counters, f32 biases, bf16-T weights ----------------
__global__ void k_setup(const void* box,
                        const void* bf1, const void* bf2, const void* b2, const void* b3,
                        const void* bo1, const void* wo2, const void* bo2,
                        const void* wf1, const void* wf2, const void* w2m, const void* w3m,
                        const void* winm, const void* wo1,
                        float* wb, unsigned short* wtT, int* pcnt, int* nclo) {
    int bf = bfflag(box);
    int bid = blockIdx.x, tid = threadIdx.x;
    if (bid == 0) {
        for (int t = tid; t < SN_NA; t += 256) nclo[t] = 0;
        if (tid == 0) *pcnt = 0;
    }
    if (bid < 7) {
        int t = bid * 256 + tid;
        if (t < NB_TOT) {
            const int   sz[7] = {384,384,384,384,64,64,1};
            const void* ps[7] = {bf1,bf2,b2,b3,bo1,wo2,bo2};
            int rem = t, s = 0;
#pragma unroll
            for (int q = 0; q < 7; q++) { if (rem >= sz[q]) { rem -= sz[q]; s = q+1; } else break; }
            wb[t] = ldr(ps[s], rem, bf);
        }
    } else {
        int t = (bid - 7) * 256 + tid;
        if (t < NT_TOT) {
            float v;
            if (t < OT_WF2T) {
                int lay = t / 8192, rem = t - lay*8192, col = rem >> 6, k = rem & 63;
                v = (k < SN_G) ? ldr(wf1, lay*(SN_G*SN_F) + k*SN_F + col, bf) : 0.0f;
            } else if (t < OT_W2T) {
                int i2 = t - OT_WF2T; int lay = i2 >> 14, rem = i2 & 16383, col = rem >> 7, k = rem & 127;
                v = ldr(wf2, lay*16384 + k*128 + col, bf);
            } else if (t < OT_W3T) {
                int i2 = t - OT_W2T;  int lay = i2 >> 14, rem = i2 & 16383, col = rem >> 7, k = rem & 127;
                v = ldr(w2m, lay*16384 + k*128 + col, bf);
            } else if (t < OT_WINT) {
                int i2 = t - OT_W3T;  int lay = i2 >> 14, rem = i2 & 16383, col = rem >> 7, k = rem & 127;
                v = ldr(w3m, lay*16384 + k*128 + col, bf);
            } else if (t < OT_WO1T) {
                int i2 = t - OT_WINT; int lay = i2 >> 14, rem = i2 & 16383, col = rem >> 7, k = rem & 127;
                v = ldr(winm, lay*16384 + k*128 + col, bf);
            } else {
                int i2 = t - OT_WO1T; int col = i2 >> 7, k = i2 & 127;
                v = ldr(wo1, k*64 + col, bf);
            }
            wtT[t] = f2bf(v);
        }
    }
}

// ---------------- pair list + split CSR build (block-aggregated) ----------------
__global__ void k_build(const void* pos, const void* box,
                        int* pcnt, int* ncup, int* nclo,
                        int* nbrp, int* nbro, float* pairr) {
    __shared__ int   lj[64];
    __shared__ float lr[64];
    __shared__ int   lsh[2];
    int bf = bfflag(box);
    int i = blockIdx.x;
    int tid = threadIdx.x;
    if (tid == 0) lsh[0] = 0;

    float c00 = ldr(box,0,bf)*10.f, c01 = ldr(box,1,bf)*10.f, c02 = ldr(box,2,bf)*10.f;
    float c10 = ldr(box,3,bf)*10.f, c11 = ldr(box,4,bf)*10.f, c12 = ldr(box,5,bf)*10.f;
    float c20 = ldr(box,6,bf)*10.f, c21 = ldr(box,7,bf)*10.f, c22 = ldr(box,8,bf)*10.f;
    float det = c00*(c11*c22 - c12*c21) - c01*(c10*c22 - c12*c20) + c02*(c10*c21 - c11*c20);
    float id  = 1.0f / det;
    float i00 = (c11*c22 - c12*c21)*id, i01 = (c02*c21 - c01*c22)*id, i02 = (c01*c12 - c02*c11)*id;
    float i10 = (c12*c20 - c10*c22)*id, i11 = (c00*c22 - c02*c20)*id, i12 = (c02*c10 - c00*c12)*id;
    float i20 = (c10*c21 - c11*c20)*id, i21 = (c01*c20 - c00*c21)*id, i22 = (c00*c11 - c01*c10)*id;

    float xi = ldr(pos, i*3+0, bf)*10.f;
    float yi = ldr(pos, i*3+1, bf)*10.f;
    float zi = ldr(pos, i*3+2, bf)*10.f;
    __syncthreads();

    for (int j = i + 1 + tid; j < SN_NA; j += 256) {
        float dx = xi - ldr(pos, j*3+0, bf)*10.f;
        float dy = yi - ldr(pos, j*3+1, bf)*10.f;
        float dz = zi - ldr(pos, j*3+2, bf)*10.f;
        float fx = dx*i00 + dy*i10 + dz*i20;
        float fy = dx*i01 + dy*i11 + dz*i21;
        float fz = dx*i02 + dy*i12 + dz*i22;
        fx -= rintf(fx); fy -= rintf(fy); fz -= rintf(fz);
        float ax = fx*c00 + fy*c10 + fz*c20;
        float ay = fx*c01 + fy*c11 + fz*c21;
        float az = fx*c02 + fy*c12 + fz*c22;
        float r2 = ax*ax + ay*ay + az*az;
        if (r2 < SN_CUT2) {
            int k = atomicAdd(&lsh[0], 1);
            if (k < 64) { lj[k] = j; lr[k] = sqrtf(r2); }
        }
    }
    __syncthreads();

    int cnt = lsh[0]; if (cnt > 64) cnt = 64;
    if (tid == 0) lsh[1] = atomicAdd(pcnt, cnt);
    __syncthreads();
    int base = lsh[1];
    int avail = SN_MAXP - base; if (avail < 0) avail = 0;
    int stored = cnt < avail ? cnt : avail;
    if (tid == 0) ncup[i] = stored;

    if (tid < stored) {
        int p = base + tid;
        int j = lj[tid];
        pairr[p] = lr[tid];
        nbrp[i*SN_MAXN + tid] = p;
        nbro[i*SN_MAXN + tid] = j;
        int kj = atomicAdd(&nclo[j], 1);
        if (kj < 64) {
            nbrp[j*SN_MAXN + 64 + kj] = p;
            nbro[j*SN_MAXN + 64 + kj] = i;
        }
    }
}

// ---------------- combined: init (blocks 0..49) + all-layer filter (50..3121) ----
// init: x = emb[zn] (f32) ; xf = x @ Win[0] via MFMA (16 atoms/block)
// filter: Wij = (ssp(g@Wf1+bf1))@Wf2+bf2 for ALL 3 layers (16 pairs/block)
// frags (m89-verified): A row=lane&15,k=(lane>>4)*8+e ; B col=lane&15 ; C col=lane&15,row=(lane>>4)*4+r
__global__ void k_initfilter(const int* zn, const void* emb, const void* box,
                             const float* pairr, const int* pcnt,
                             const float* wb, const unsigned short* wtT,
                             float* x, float* xf, unsigned short* wph) {
    __shared__ unsigned short es[16][136];
    __shared__ unsigned short gls[16][72];
    __shared__ unsigned short hls[16][136];
    int tid  = threadIdx.x;
    int lane = tid & 63;
    int wave = tid >> 6;
    int rowA = lane & 15;
    int kgrp = lane >> 4;

    if (blockIdx.x < 50) {
        // ---- init ----
        int bf = bfflag(box);
        int a0 = blockIdx.x * 16;
        int a = tid >> 4, f0 = (tid & 15) * 8;
        int atom = a0 + a;
        int z = zn[atom];
        float v[8];
#pragma unroll
        for (int q = 0; q < 8; q++) v[q] = ldr(emb, z*SN_F + f0 + q, bf);
        *(float4*)&x[atom*SN_F + f0]     = make_float4(v[0],v[1],v[2],v[3]);
        *(float4*)&x[atom*SN_F + f0 + 4] = make_float4(v[4],v[5],v[6],v[7]);
#pragma unroll
        for (int q = 0; q < 8; q++) es[a][f0+q] = f2bf(v[q]);
        __syncthreads();

        int c0 = wave * 32;
        f32x4 acc0 = {0.f,0.f,0.f,0.f}, acc1 = {0.f,0.f,0.f,0.f};
        const unsigned short* wn = wtT + OT_WINT;   // layer 0
#pragma unroll
        for (int ks = 0; ks < 4; ks++) {
            short8 a8 = *(const short8*)&es[rowA][ks*32 + kgrp*8];
            short8 w0 = *(const short8*)(wn + (c0 + rowA)*128      + ks*32 + kgrp*8);
            short8 w1 = *(const short8*)(wn + (c0 + 16 + rowA)*128 + ks*32 + kgrp*8);
            acc0 = __builtin_amdgcn_mfma_f32_16x16x32_bf16(a8, w0, acc0, 0, 0, 0);
            acc1 = __builtin_amdgcn_mfma_f32_16x16x32_bf16(a8, w1, acc1, 0, 0, 0);
        }
#pragma unroll
        for (int r = 0; r < 4; r++) {
            int row = kgrp*4 + r;
            xf[(a0 + row)*SN_F + c0 + rowA]      = acc0[r];
            xf[(a0 + row)*SN_F + c0 + 16 + rowA] = acc1[r];
        }
        return;
    }

    // ---- filter, all layers ----
    int fb  = blockIdx.x - 50;
    int lay = fb >> 10;
    int p0  = (fb & 1023) * 16;
    int cnt = *pcnt; if (cnt > SN_MAXP) cnt = SN_MAXP;
    if (p0 >= cnt) return;
    int c0 = wave * 32;

    {
        int pr = tid >> 4, k0 = (tid & 15) * 4;
        int p = p0 + pr;
        float r = (p < cnt) ? pairr[p] : -1.0f;
        const float width = 5.0f/49.0f, gamma = 0.5f/(width*width);
        unsigned short gv[4];
#pragma unroll
        for (int q = 0; q < 4; q++) {
            int k = k0 + q;
            float g = 0.f;
            if (k < SN_G && r >= 0.f) { float d = r - width*(float)k; g = __expf(-gamma*d*d); }
            gv[q] = f2bf(g);
        }
        *(unsigned long long*)&gls[pr][k0] = *(unsigned long long*)gv;
    }
    __syncthreads();

    f32x4 acc0 = {0.f,0.f,0.f,0.f}, acc1 = {0.f,0.f,0.f,0.f};
    const unsigned short* b1 = wtT + OT_WF1T + lay*8192;
#pragma unroll
    for (int ks = 0; ks < 2; ks++) {
        short8 a8 = *(const short8*)&gls[rowA][ks*32 + kgrp*8];
        short8 w0 = *(const short8*)(b1 + (c0 + rowA)*64      + ks*32 + kgrp*8);
        short8 w1 = *(const short8*)(b1 + (c0 + 16 + rowA)*64 + ks*32 + kgrp*8);
        acc0 = __builtin_amdgcn_mfma_f32_16x16x32_bf16(a8, w0, acc0, 0, 0, 0);
        acc1 = __builtin_amdgcn_mfma_f32_16x16x32_bf16(a8, w1, acc1, 0, 0, 0);
    }
    {
        float b1c0 = wb[OB_BF1 + lay*SN_F + c0 + rowA];
        float b1c1 = wb[OB_BF1 + lay*SN_F + c0 + 16 + rowA];
#pragma unroll
        for (int r = 0; r < 4; r++) {
            int row = kgrp*4 + r;
            hls[row][c0 + rowA]      = f2bf(sspf(acc0[r] + b1c0));
            hls[row][c0 + 16 + rowA] = f2bf(sspf(acc1[r] + b1c1));
        }
    }
    __syncthreads();

    f32x4 d0 = {0.f,0.f,0.f,0.f}, d1 = {0.f,0.f,0.f,0.f};
    const unsigned short* b2w = wtT + OT_WF2T + lay*16384;
#pragma unroll
    for (int ks = 0; ks < 4; ks++) {
        short8 a8 = *(const short8*)&hls[rowA][ks*32 + kgrp*8];
        short8 w0 = *(const short8*)(b2w + (c0 + rowA)*128      + ks*32 + kgrp*8);
        short8 w1 = *(const short8*)(b2w + (c0 + 16 + rowA)*128 + ks*32 + kgrp*8);
        d0 = __builtin_amdgcn_mfma_f32_16x16x32_bf16(a8, w0, d0, 0, 0, 0);
        d1 = __builtin_amdgcn_mfma_f32_16x16x32_bf16(a8, w1, d1, 0, 0, 0);
    }
    {
        unsigned short* wout = wph + lay*(SN_MAXP*SN_F);
        float b2c0 = wb[OB_BF2 + lay*SN_F + c0 + rowA];
        float b2c1 = wb[OB_BF2 + lay*SN_F + c0 + 16 + rowA];
#pragma unroll
        for (int r = 0; r < 4; r++) {
            int p = p0 + kgrp*4 + r;    // pad rows never referenced by CSR
            wout[p*SN_F + c0 + rowA]      = f2bf(d0[r] + b2c0);
            wout[p*SN_F + c0 + 16 + rowA] = f2bf(d1[r] + b2c1);
        }
    }
}

// ---------------- per-layer: gather + 3 MFMA GEMMs + residual ----------------
// 50 blocks x 512 threads (8 waves; wave w owns cols [w*16, w*16+16)).
__global__ void k_layerM(const int* ncup, const int* nclo,
                         const int* nbrp, const int* nbro,
                         const unsigned short* wph, const float* xf_in, float* x,
                         const float* wb, const unsigned short* wtT,
                         int lay, int layNext, float* xf_out, unsigned short* xh) {
    __shared__ int   spA[16][128], sjA[16][128];
    __shared__ unsigned short ms[16][136], ts[16][136], xs[16][136];
    int tid = threadIdx.x;
    int a0 = blockIdx.x * 16;
    int a = tid >> 5, l32 = tid & 31;
    int atom = a0 + a;
    int up = ncup[atom]; if (up > 64) up = 64;
    int lo = nclo[atom]; if (lo > 64) lo = 64;
    int cn = up + lo;
    for (int k = l32; k < up; k += 32) {
        spA[a][k] = nbrp[atom*SN_MAXN + k];
        sjA[a][k] = nbro[atom*SN_MAXN + k];
    }
    for (int k = l32; k < lo; k += 32) {
        spA[a][up + k] = nbrp[atom*SN_MAXN + 64 + k];
        sjA[a][up + k] = nbro[atom*SN_MAXN + 64 + k];
    }
    __syncthreads();

    // gather m[a][f] = sum_k Wpk[f]*xf[jk][f]
    {
        int f0 = l32 * 4;
        float acc[4] = {0.f,0.f,0.f,0.f};
        const unsigned short* wpb = wph + lay*(SN_MAXP*SN_F);
        int k = 0;
        for (; k + 2 <= cn; k += 2) {
            int p0 = spA[a][k],   j0 = sjA[a][k];
            int p1 = spA[a][k+1], j1 = sjA[a][k+1];
            ushort4 w0 = *(const ushort4*)(wpb + p0*SN_F + f0);
            ushort4 w1 = *(const ushort4*)(wpb + p1*SN_F + f0);
            float4  xa = *(const float4*)(xf_in + j0*SN_F + f0);
            float4  xb = *(const float4*)(xf_in + j1*SN_F + f0);
            acc[0] = fmaf(bf2f(w0.x), xa.x, fmaf(bf2f(w1.x), xb.x, acc[0]));
            acc[1] = fmaf(bf2f(w0.y), xa.y, fmaf(bf2f(w1.y), xb.y, acc[1]));
            acc[2] = fmaf(bf2f(w0.z), xa.z, fmaf(bf2f(w1.z), xb.z, acc[2]));
            acc[3] = fmaf(bf2f(w0.w), xa.w, fmaf(bf2f(w1.w), xb.w, acc[3]));
        }
        if (k < cn) {
            int p0 = spA[a][k], j0 = sjA[a][k];
            ushort4 w0 = *(const ushort4*)(wpb + p0*SN_F + f0);
            float4  xa = *(const float4*)(xf_in + j0*SN_F + f0);
            acc[0] = fmaf(bf2f(w0.x), xa.x, acc[0]);
            acc[1] = fmaf(bf2f(w0.y), xa.y, acc[1]);
            acc[2] = fmaf(bf2f(w0.z), xa.z, acc[2]);
            acc[3] = fmaf(bf2f(w0.w), xa.w, acc[3]);
        }
#pragma unroll
        for (int q = 0; q < 4; q++) ms[a][f0+q] = f2bf(acc[q]);
    }
    __syncthreads();

    int lane = tid & 63;
    int wave = tid >> 6;
    int c0   = wave * 16;
    int rowA = lane & 15;
    int kgrp = lane >> 4;
    int col  = c0 + rowA;

    // GEMM1: t = ssp(m @ W2 + b2)
    {
        f32x4 acc = {0.f,0.f,0.f,0.f};
        const unsigned short* w = wtT + OT_W2T + lay*16384;
#pragma unroll
        for (int ks = 0; ks < 4; ks++) {
            short8 a8 = *(const short8*)&ms[rowA][ks*32 + kgrp*8];
            short8 w8 = *(const short8*)(w + col*128 + ks*32 + kgrp*8);
            acc = __builtin_amdgcn_mfma_f32_16x16x32_bf16(a8, w8, acc, 0, 0, 0);
        }
        float bc = wb[OB_B2 + lay*SN_F + col];
#pragma unroll
        for (int r = 0; r < 4; r++) ts[kgrp*4 + r][col] = f2bf(sspf(acc[r] + bc));
    }
    __syncthreads();

    // GEMM2: v = t @ W3 + b3 ; xnew = x + v
    {
        f32x4 acc = {0.f,0.f,0.f,0.f};
        const unsigned short* w = wtT + OT_W3T + lay*16384;
#pragma unroll
        for (int ks = 0; ks < 4; ks++) {
            short8 a8 = *(const short8*)&ts[rowA][ks*32 + kgrp*8];
            short8 w8 = *(const short8*)(w + col*128 + ks*32 + kgrp*8);
            acc = __builtin_amdgcn_mfma_f32_16x16x32_bf16(a8, w8, acc, 0, 0, 0);
        }
        float bc = wb[OB_B3 + lay*SN_F + col];
#pragma unroll
        for (int r = 0; r < 4; r++) {
            int row = kgrp*4 + r;
            float xnew = x[(a0 + row)*SN_F + col] + acc[r] + bc;
            x[(a0 + row)*SN_F + col] = xnew;
            if (layNext >= 0) xs[row][col] = f2bf(xnew);
            else              xh[(a0 + row)*SN_F + col] = f2bf(xnew);
        }
    }

    if (layNext >= 0) {
        __syncthreads();
        // GEMM3: xf_out = xnew @ Win[layNext]
        f32x4 acc = {0.f,0.f,0.f,0.f};
        const unsigned short* w = wtT + OT_WINT + layNext*16384;
#pragma unroll
        for (int ks = 0; ks < 4; ks++) {
            short8 a8 = *(const short8*)&xs[rowA][ks*32 + kgrp*8];
            short8 w8 = *(const short8*)(w + col*128 + ks*32 + kgrp*8);
            acc = __builtin_amdgcn_mfma_f32_16x16x32_bf16(a8, w8, acc, 0, 0, 0);
        }
#pragma unroll
        for (int r = 0; r < 4; r++)
            xf_out[(a0 + kgrp*4 + r)*SN_F + col] = acc[r];
    }
}

// ---------------- fused energy head + reduce (1 block, 512 thr, MFMA) --------
__global__ void k_headred(const unsigned short* xh, const float* wb,
                          const unsigned short* wtT, const void* box, void* out) {
    __shared__ float red[512];
    int tid  = threadIdx.x;
    int lane = tid & 63;
    int wave = tid >> 6;
    int ct   = wave & 3;        // col-tile of 64-wide head output
    int astart = wave >> 2;     // atom-tile stride-2 split
    int rowA = lane & 15;
    int kgrp = lane >> 4;
    int col  = ct*16 + rowA;
    float bo1c = wb[OB_BO1 + col];
    float wo2c = wb[OB_WO2 + col];
    const unsigned short* w = wtT + OT_WO1T;

    float e = 0.f;
    for (int at = astart; at < 50; at += 2) {
        f32x4 acc = {0.f,0.f,0.f,0.f};
#pragma unroll
        for (int ks = 0; ks < 4; ks++) {
            short8 a8 = *(const short8*)(xh + (at*16 + rowA)*SN_F + ks*32 + kgrp*8);
            short8 w8 = *(const short8*)(w + col*128 + ks*32 + kgrp*8);
            acc = __builtin_amdgcn_mfma_f32_16x16x32_bf16(a8, w8, acc, 0, 0, 0);
        }
#pragma unroll
        for (int r = 0; r < 4; r++) e += sspf(acc[r] + bo1c) * wo2c;
    }
    red[tid] = e;
    __syncthreads();
    for (int wd = 256; wd > 0; wd >>= 1) {
        if (tid < wd) red[tid] += red[tid + wd];
        __syncthreads();
    }
    if (tid == 0) {
        float v = red[0] + (float)SN_NA * wb[OB_BO2];
        if (bfflag(box)) ((unsigned short*)out)[0] = f2bf(v);
        else             ((float*)out)[0] = v;
    }
}

__global__ void k_fail(void* out) {
    ((unsigned short*)out)[0] = 0x449A;   // bf16 1234.0 sentinel
}

extern "C" void kernel_launch(void* const* d_in, const int* in_sizes, int n_in,
                              void* d_out, int out_size, void* d_ws, size_t ws_size,
                              hipStream_t stream)
{
    const void* pos = d_in[0];
    const void* box = d_in[1];
    const int*  zn  = (const int*)d_in[2];
    const void* emb = d_in[3];

    if (ws_size < (size_t)SN_WSNEED) {
        k_fail<<<1, 1, 0, stream>>>(d_out);
        return;
    }

    char* ws = (char*)d_ws;
    int*            pcnt  = (int*)           (ws + WO_PCNT);
    int*            ncup  = (int*)           (ws + WO_NCUP);
    int*            nclo  = (int*)           (ws + WO_NCLO);
    int*            nbrp  = (int*)           (ws + WO_NBRP);
    int*            nbro  = (int*)           (ws + WO_NBRO);
    float*          pairr = (float*)         (ws + WO_PAIRR);
    float*          wb    = (float*)         (ws + WO_WB);
    unsigned short* wtT   = (unsigned short*)(ws + WO_WTT);
    unsigned short* wph   = (unsigned short*)(ws + WO_WPH);
    float*          x     = (float*)         (ws + WO_X);
    float*          xfA   = (float*)         (ws + WO_XF);
    float*          xfB   = (float*)         (ws + WO_XF2);
    unsigned short* xh    = (unsigned short*)(ws + WO_XH);

    k_setup<<<903, 256, 0, stream>>>(box,
        d_in[5], d_in[7], d_in[10], d_in[12], d_in[14], d_in[15], d_in[16],
        d_in[4], d_in[6], d_in[9], d_in[11], d_in[8], d_in[13],
        wb, wtT, pcnt, nclo);
    k_build<<<SN_NA, 256, 0, stream>>>(pos, box, pcnt, ncup, nclo, nbrp, nbro, pairr);
    k_initfilter<<<50 + 3*1024, 256, 0, stream>>>(zn, emb, box, pairr, pcnt,
                                                  wb, wtT, x, xfA, wph);

    float* xf_in = xfA;
    float* xf_out = xfB;
    for (int l = 0; l < 3; l++) {
        int layNext = (l < 2) ? (l + 1) : -1;
        k_layerM<<<50, 512, 0, stream>>>(ncup, nclo, nbrp, nbro, wph, xf_in, x,
                                         wb, wtT, l, layNext, xf_out, xh);
        float* t = xf_in; xf_in = xf_out; xf_out = t;
    }

    k_headred<<<1, 512, 0, stream>>>(xh, wb, wtT, box, d_out);
}

// Round 8
// 95.680 us; speedup vs baseline: 5.8730x; 1.4573x over previous
//
#include <hip/hip_runtime.h>

#define SN_NA    800
#define SN_F     128
#define SN_G     50
#define SN_MAXP  16384
#define SN_MAXN  128      // row slots: upper [0,64), lower [64,128)
#define SN_CUT2  25.0f

typedef __attribute__((ext_vector_type(4))) float f32x4;
typedef __attribute__((ext_vector_type(8))) short short8;

// ---- f32 bias offsets (elements, inside wb) ----
#define OB_BF1 0        // [3][128]
#define OB_BF2 384
#define OB_B2  768
#define OB_B3  1152
#define OB_BO1 1536     // [64]
#define OB_WO2 1600     // [64]
#define OB_BO2 1664     // [1]
#define NB_TOT 1665

// ---- bf16 transposed weights (elements, inside wtT): wT[col][k] = W[k][col] ----
#define OT_WF1T 0        // [3][128][64] (k>=50 zero)
#define OT_WF2T 24576    // [3][128][128]
#define OT_W2T  73728    // [3][128][128]
#define OT_W3T  122880   // [3][128][128]
#define OT_WINT 172032   // [3][128][128]
#define OT_WO1T 221184   // [64][128]
#define NT_TOT  229376

// ---- ws layout (bytes) ----
#define WO_PCNT  0
#define WO_NCUP  64
#define WO_NCLO  3264
#define WO_NBRP  6464
#define WO_NBRO  (WO_NBRP + SN_NA*SN_MAXN*4)
#define WO_PAIRR (WO_NBRO + SN_NA*SN_MAXN*4)
#define WO_WB    (WO_PAIRR + SN_MAXP*4)
#define WO_WTT   ((WO_WB + NB_TOT*4 + 15) & ~15)
#define WO_WPH   ((WO_WTT + NT_TOT*2 + 15) & ~15)
#define WO_X     (WO_WPH + 3*SN_MAXP*SN_F*2)
#define WO_XF    (WO_X  + SN_NA*SN_F*4)
#define WO_XF2   (WO_XF + SN_NA*SN_F*4)
#define WO_XH    (WO_XF2 + SN_NA*SN_F*4)
#define WO_EPART (WO_XH + SN_NA*SN_F*2)
#define SN_WSNEED (WO_EPART + 64*4)

// runtime dtype-generic scalar load
__device__ __forceinline__ float ldr(const void* p, int idx, int bf) {
    if (bf) {
        unsigned int x = ((unsigned int)(((const unsigned short*)p)[idx])) << 16;
        float f; __builtin_memcpy(&f, &x, 4); return f;
    }
    return ((const float*)p)[idx];
}
__device__ __forceinline__ int bfflag(const void* box) {
    float b0 = ((const float*)box)[0];    // f32: ~2.3 ; bf16 pair reinterpreted: denormal
    return !(b0 > 1e-3f && b0 < 1e3f);
}
__device__ __forceinline__ float bf2f(unsigned short u) {
    unsigned int x = ((unsigned int)u) << 16;
    float f; __builtin_memcpy(&f, &x, 4); return f;
}
__device__ __forceinline__ unsigned short f2bf(float v) {
    unsigned int b; __builtin_memcpy(&b, &v, 4);
    return (unsigned short)((b + 0x7FFFu + ((b >> 16) & 1u)) >> 16);
}
__device__ __forceinline__ float sspf(float v) {
    float sp = fmaxf(v, 0.0f) + log1pf(__expf(-fabsf(v)));
    return sp - 0.69314718055994530942f;
}

// ---------------- setup: zero counters, f32 biases, bf16-T weights ----------------
__global__ void k_setup(const void* box,
                        const void* bf1, const void* bf2, const void* b2, const void* b3,
                        const void* bo1, const void* wo2, const void* bo2,
                        const void* wf1, const void* wf2, const void* w2m, const void* w3m,
                        const void* winm, const void* wo1,
                        float* wb, unsigned short* wtT, int* pcnt, int* nclo) {
    int bf = bfflag(box);
    int bid = blockIdx.x, tid = threadIdx.x;
    if (bid == 0) {
        for (int t = tid; t < SN_NA; t += 256) nclo[t] = 0;
        if (tid == 0) *pcnt = 0;
    }
    if (bid < 7) {
        int t = bid * 256 + tid;
        if (t < NB_TOT) {
            const int   sz[7] = {384,384,384,384,64,64,1};
            const void* ps[7] = {bf1,bf2,b2,b3,bo1,wo2,bo2};
            int rem = t, s = 0;
#pragma unroll
            for (int q = 0; q < 7; q++) { if (rem >= sz[q]) { rem -= sz[q]; s = q+1; } else break; }
            wb[t] = ldr(ps[s], rem, bf);
        }
    } else {
        int t = (bid - 7) * 256 + tid;
        if (t < NT_TOT) {
            float v;
            if (t < OT_WF2T) {
                int lay = t / 8192, rem = t - lay*8192, col = rem >> 6, k = rem & 63;
                v = (k < SN_G) ? ldr(wf1, lay*(SN_G*SN_F) + k*SN_F + col, bf) : 0.0f;
            } else if (t < OT_W2T) {
                int i2 = t - OT_WF2T; int lay = i2 >> 14, rem = i2 & 16383, col = rem >> 7, k = rem & 127;
                v = ldr(wf2, lay*16384 + k*128 + col, bf);
            } else if (t < OT_W3T) {
                int i2 = t - OT_W2T;  int lay = i2 >> 14, rem = i2 & 16383, col = rem >> 7, k = rem & 127;
                v = ldr(w2m, lay*16384 + k*128 + col, bf);
            } else if (t < OT_WINT) {
                int i2 = t - OT_W3T;  int lay = i2 >> 14, rem = i2 & 16383, col = rem >> 7, k = rem & 127;
                v = ldr(w3m, lay*16384 + k*128 + col, bf);
            } else if (t < OT_WO1T) {
                int i2 = t - OT_WINT; int lay = i2 >> 14, rem = i2 & 16383, col = rem >> 7, k = rem & 127;
                v = ldr(winm, lay*16384 + k*128 + col, bf);
            } else {
                int i2 = t - OT_WO1T; int col = i2 >> 7, k = i2 & 127;
                v = ldr(wo1, k*64 + col, bf);
            }
            wtT[t] = f2bf(v);
        }
    }
}

// ---------------- pair list + split CSR build (block-aggregated) ----------------
__global__ void k_build(const void* pos, const void* box,
                        int* pcnt, int* ncup, int* nclo,
                        int* nbrp, int* nbro, float* pairr) {
    __shared__ int   lj[64];
    __shared__ float lr[64];
    __shared__ int   lsh[2];
    int bf = bfflag(box);
    int i = blockIdx.x;
    int tid = threadIdx.x;
    if (tid == 0) lsh[0] = 0;

    float c00 = ldr(box,0,bf)*10.f, c01 = ldr(box,1,bf)*10.f, c02 = ldr(box,2,bf)*10.f;
    float c10 = ldr(box,3,bf)*10.f, c11 = ldr(box,4,bf)*10.f, c12 = ldr(box,5,bf)*10.f;
    float c20 = ldr(box,6,bf)*10.f, c21 = ldr(box,7,bf)*10.f, c22 = ldr(box,8,bf)*10.f;
    float det = c00*(c11*c22 - c12*c21) - c01*(c10*c22 - c12*c20) + c02*(c10*c21 - c11*c20);
    float id  = 1.0f / det;
    float i00 = (c11*c22 - c12*c21)*id, i01 = (c02*c21 - c01*c22)*id, i02 = (c01*c12 - c02*c11)*id;
    float i10 = (c12*c20 - c10*c22)*id, i11 = (c00*c22 - c02*c20)*id, i12 = (c02*c10 - c00*c12)*id;
    float i20 = (c10*c21 - c11*c20)*id, i21 = (c01*c20 - c00*c21)*id, i22 = (c00*c11 - c01*c10)*id;

    float xi = ldr(pos, i*3+0, bf)*10.f;
    float yi = ldr(pos, i*3+1, bf)*10.f;
    float zi = ldr(pos, i*3+2, bf)*10.f;
    __syncthreads();

    for (int j = i + 1 + tid; j < SN_NA; j += 256) {
        float dx = xi - ldr(pos, j*3+0, bf)*10.f;
        float dy = yi - ldr(pos, j*3+1, bf)*10.f;
        float dz = zi - ldr(pos, j*3+2, bf)*10.f;
        float fx = dx*i00 + dy*i10 + dz*i20;
        float fy = dx*i01 + dy*i11 + dz*i21;
        float fz = dx*i02 + dy*i12 + dz*i22;
        fx -= rintf(fx); fy -= rintf(fy); fz -= rintf(fz);
        float ax = fx*c00 + fy*c10 + fz*c20;
        float ay = fx*c01 + fy*c11 + fz*c21;
        float az = fx*c02 + fy*c12 + fz*c22;
        float r2 = ax*ax + ay*ay + az*az;
        if (r2 < SN_CUT2) {
            int k = atomicAdd(&lsh[0], 1);
            if (k < 64) { lj[k] = j; lr[k] = sqrtf(r2); }
        }
    }
    __syncthreads();

    int cnt = lsh[0]; if (cnt > 64) cnt = 64;
    if (tid == 0) lsh[1] = atomicAdd(pcnt, cnt);
    __syncthreads();
    int base = lsh[1];
    int avail = SN_MAXP - base; if (avail < 0) avail = 0;
    int stored = cnt < avail ? cnt : avail;
    if (tid == 0) ncup[i] = stored;

    if (tid < stored) {
        int p = base + tid;
        int j = lj[tid];
        pairr[p] = lr[tid];
        nbrp[i*SN_MAXN + tid] = p;
        nbro[i*SN_MAXN + tid] = j;
        int kj = atomicAdd(&nclo[j], 1);
        if (kj < 64) {
            nbrp[j*SN_MAXN + 64 + kj] = p;
            nbro[j*SN_MAXN + 64 + kj] = i;
        }
    }
}

// ---------------- combined: init (blocks 0..49) + all-layer filter (50..3121) ----
// frags (m89-verified): A row=lane&15,k=(lane>>4)*8+e ; B col=lane&15 ; C col=lane&15,row=(lane>>4)*4+r
__global__ void k_initfilter(const int* zn, const void* emb, const void* box,
                             const float* pairr, const int* pcnt,
                             const float* wb, const unsigned short* wtT,
                             float* x, float* xf, unsigned short* wph) {
    __shared__ unsigned short es[16][136];
    __shared__ unsigned short gls[16][72];
    __shared__ unsigned short hls[16][136];
    int tid  = threadIdx.x;
    int lane = tid & 63;
    int wave = tid >> 6;
    int rowA = lane & 15;
    int kgrp = lane >> 4;

    if (blockIdx.x < 50) {
        // ---- init ----
        int bf = bfflag(box);
        int a0 = blockIdx.x * 16;
        int a = tid >> 4, f0 = (tid & 15) * 8;
        int atom = a0 + a;
        int z = zn[atom];
        float v[8];
#pragma unroll
        for (int q = 0; q < 8; q++) v[q] = ldr(emb, z*SN_F + f0 + q, bf);
        *(float4*)&x[atom*SN_F + f0]     = make_float4(v[0],v[1],v[2],v[3]);
        *(float4*)&x[atom*SN_F + f0 + 4] = make_float4(v[4],v[5],v[6],v[7]);
#pragma unroll
        for (int q = 0; q < 8; q++) es[a][f0+q] = f2bf(v[q]);
        __syncthreads();

        int c0 = wave * 32;
        f32x4 acc0 = {0.f,0.f,0.f,0.f}, acc1 = {0.f,0.f,0.f,0.f};
        const unsigned short* wn = wtT + OT_WINT;   // layer 0
#pragma unroll
        for (int ks = 0; ks < 4; ks++) {
            short8 a8 = *(const short8*)&es[rowA][ks*32 + kgrp*8];
            short8 w0 = *(const short8*)(wn + (c0 + rowA)*128      + ks*32 + kgrp*8);
            short8 w1 = *(const short8*)(wn + (c0 + 16 + rowA)*128 + ks*32 + kgrp*8);
            acc0 = __builtin_amdgcn_mfma_f32_16x16x32_bf16(a8, w0, acc0, 0, 0, 0);
            acc1 = __builtin_amdgcn_mfma_f32_16x16x32_bf16(a8, w1, acc1, 0, 0, 0);
        }
#pragma unroll
        for (int r = 0; r < 4; r++) {
            int row = kgrp*4 + r;
            xf[(a0 + row)*SN_F + c0 + rowA]      = acc0[r];
            xf[(a0 + row)*SN_F + c0 + 16 + rowA] = acc1[r];
        }
        return;
    }

    // ---- filter, all layers ----
    int fb  = blockIdx.x - 50;
    int lay = fb >> 10;
    int p0  = (fb & 1023) * 16;
    int cnt = *pcnt; if (cnt > SN_MAXP) cnt = SN_MAXP;
    if (p0 >= cnt) return;
    int c0 = wave * 32;

    {
        int pr = tid >> 4, k0 = (tid & 15) * 4;
        int p = p0 + pr;
        float r = (p < cnt) ? pairr[p] : -1.0f;
        const float width = 5.0f/49.0f, gamma = 0.5f/(width*width);
        unsigned short gv[4];
#pragma unroll
        for (int q = 0; q < 4; q++) {
            int k = k0 + q;
            float g = 0.f;
            if (k < SN_G && r >= 0.f) { float d = r - width*(float)k; g = __expf(-gamma*d*d); }
            gv[q] = f2bf(g);
        }
        *(unsigned long long*)&gls[pr][k0] = *(unsigned long long*)gv;
    }
    __syncthreads();

    f32x4 acc0 = {0.f,0.f,0.f,0.f}, acc1 = {0.f,0.f,0.f,0.f};
    const unsigned short* b1 = wtT + OT_WF1T + lay*8192;
#pragma unroll
    for (int ks = 0; ks < 2; ks++) {
        short8 a8 = *(const short8*)&gls[rowA][ks*32 + kgrp*8];
        short8 w0 = *(const short8*)(b1 + (c0 + rowA)*64      + ks*32 + kgrp*8);
        short8 w1 = *(const short8*)(b1 + (c0 + 16 + rowA)*64 + ks*32 + kgrp*8);
        acc0 = __builtin_amdgcn_mfma_f32_16x16x32_bf16(a8, w0, acc0, 0, 0, 0);
        acc1 = __builtin_amdgcn_mfma_f32_16x16x32_bf16(a8, w1, acc1, 0, 0, 0);
    }
    {
        float b1c0 = wb[OB_BF1 + lay*SN_F + c0 + rowA];
        float b1c1 = wb[OB_BF1 + lay*SN_F + c0 + 16 + rowA];
#pragma unroll
        for (int r = 0; r < 4; r++) {
            int row = kgrp*4 + r;
            hls[row][c0 + rowA]      = f2bf(sspf(acc0[r] + b1c0));
            hls[row][c0 + 16 + rowA] = f2bf(sspf(acc1[r] + b1c1));
        }
    }
    __syncthreads();

    f32x4 d0 = {0.f,0.f,0.f,0.f}, d1 = {0.f,0.f,0.f,0.f};
    const unsigned short* b2w = wtT + OT_WF2T + lay*16384;
#pragma unroll
    for (int ks = 0; ks < 4; ks++) {
        short8 a8 = *(const short8*)&hls[rowA][ks*32 + kgrp*8];
        short8 w0 = *(const short8*)(b2w + (c0 + rowA)*128      + ks*32 + kgrp*8);
        short8 w1 = *(const short8*)(b2w + (c0 + 16 + rowA)*128 + ks*32 + kgrp*8);
        d0 = __builtin_amdgcn_mfma_f32_16x16x32_bf16(a8, w0, d0, 0, 0, 0);
        d1 = __builtin_amdgcn_mfma_f32_16x16x32_bf16(a8, w1, d1, 0, 0, 0);
    }
    {
        unsigned short* wout = wph + lay*(SN_MAXP*SN_F);
        float b2c0 = wb[OB_BF2 + lay*SN_F + c0 + rowA];
        float b2c1 = wb[OB_BF2 + lay*SN_F + c0 + 16 + rowA];
#pragma unroll
        for (int r = 0; r < 4; r++) {
            int p = p0 + kgrp*4 + r;    // pad rows never referenced by CSR
            wout[p*SN_F + c0 + rowA]      = f2bf(d0[r] + b2c0);
            wout[p*SN_F + c0 + 16 + rowA] = f2bf(d1[r] + b2c1);
        }
    }
}

// ---------------- per-layer: gather + 3 MFMA GEMMs + residual ----------------
// 50 blocks x 512 threads (8 waves; wave w owns cols [w*16, w*16+16)).
__global__ void k_layerM(const int* ncup, const int* nclo,
                         const int* nbrp, const int* nbro,
                         const unsigned short* wph, const float* xf_in, float* x,
                         const float* wb, const unsigned short* wtT,
                         int lay, int layNext, float* xf_out, unsigned short* xh) {
    __shared__ int   spA[16][128], sjA[16][128];
    __shared__ unsigned short ms[16][136], ts[16][136], xs[16][136];
    int tid = threadIdx.x;
    int a0 = blockIdx.x * 16;
    int a = tid >> 5, l32 = tid & 31;
    int atom = a0 + a;
    int up = ncup[atom]; if (up > 64) up = 64;
    int lo = nclo[atom]; if (lo > 64) lo = 64;
    int cn = up + lo;
    for (int k = l32; k < up; k += 32) {
        spA[a][k] = nbrp[atom*SN_MAXN + k];
        sjA[a][k] = nbro[atom*SN_MAXN + k];
    }
    for (int k = l32; k < lo; k += 32) {
        spA[a][up + k] = nbrp[atom*SN_MAXN + 64 + k];
        sjA[a][up + k] = nbro[atom*SN_MAXN + 64 + k];
    }
    __syncthreads();

    // gather m[a][f] = sum_k Wpk[f]*xf[jk][f]
    {
        int f0 = l32 * 4;
        float acc[4] = {0.f,0.f,0.f,0.f};
        const unsigned short* wpb = wph + lay*(SN_MAXP*SN_F);
        int k = 0;
        for (; k + 2 <= cn; k += 2) {
            int p0 = spA[a][k],   j0 = sjA[a][k];
            int p1 = spA[a][k+1], j1 = sjA[a][k+1];
            ushort4 w0 = *(const ushort4*)(wpb + p0*SN_F + f0);
            ushort4 w1 = *(const ushort4*)(wpb + p1*SN_F + f0);
            float4  xa = *(const float4*)(xf_in + j0*SN_F + f0);
            float4  xb = *(const float4*)(xf_in + j1*SN_F + f0);
            acc[0] = fmaf(bf2f(w0.x), xa.x, fmaf(bf2f(w1.x), xb.x, acc[0]));
            acc[1] = fmaf(bf2f(w0.y), xa.y, fmaf(bf2f(w1.y), xb.y, acc[1]));
            acc[2] = fmaf(bf2f(w0.z), xa.z, fmaf(bf2f(w1.z), xb.z, acc[2]));
            acc[3] = fmaf(bf2f(w0.w), xa.w, fmaf(bf2f(w1.w), xb.w, acc[3]));
        }
        if (k < cn) {
            int p0 = spA[a][k], j0 = sjA[a][k];
            ushort4 w0 = *(const ushort4*)(wpb + p0*SN_F + f0);
            float4  xa = *(const float4*)(xf_in + j0*SN_F + f0);
            acc[0] = fmaf(bf2f(w0.x), xa.x, acc[0]);
            acc[1] = fmaf(bf2f(w0.y), xa.y, acc[1]);
            acc[2] = fmaf(bf2f(w0.z), xa.z, acc[2]);
            acc[3] = fmaf(bf2f(w0.w), xa.w, acc[3]);
        }
#pragma unroll
        for (int q = 0; q < 4; q++) ms[a][f0+q] = f2bf(acc[q]);
    }
    __syncthreads();

    int lane = tid & 63;
    int wave = tid >> 6;
    int c0   = wave * 16;
    int rowA = lane & 15;
    int kgrp = lane >> 4;
    int col  = c0 + rowA;

    // GEMM1: t = ssp(m @ W2 + b2)
    {
        f32x4 acc = {0.f,0.f,0.f,0.f};
        const unsigned short* w = wtT + OT_W2T + lay*16384;
#pragma unroll
        for (int ks = 0; ks < 4; ks++) {
            short8 a8 = *(const short8*)&ms[rowA][ks*32 + kgrp*8];
            short8 w8 = *(const short8*)(w + col*128 + ks*32 + kgrp*8);
            acc = __builtin_amdgcn_mfma_f32_16x16x32_bf16(a8, w8, acc, 0, 0, 0);
        }
        float bc = wb[OB_B2 + lay*SN_F + col];
#pragma unroll
        for (int r = 0; r < 4; r++) ts[kgrp*4 + r][col] = f2bf(sspf(acc[r] + bc));
    }
    __syncthreads();

    // GEMM2: v = t @ W3 + b3 ; xnew = x + v
    {
        f32x4 acc = {0.f,0.f,0.f,0.f};
        const unsigned short* w = wtT + OT_W3T + lay*16384;
#pragma unroll
        for (int ks = 0; ks < 4; ks++) {
            short8 a8 = *(const short8*)&ts[rowA][ks*32 + kgrp*8];
            short8 w8 = *(const short8*)(w + col*128 + ks*32 + kgrp*8);
            acc = __builtin_amdgcn_mfma_f32_16x16x32_bf16(a8, w8, acc, 0, 0, 0);
        }
        float bc = wb[OB_B3 + lay*SN_F + col];
#pragma unroll
        for (int r = 0; r < 4; r++) {
            int row = kgrp*4 + r;
            float xnew = x[(a0 + row)*SN_F + col] + acc[r] + bc;
            x[(a0 + row)*SN_F + col] = xnew;
            if (layNext >= 0) xs[row][col] = f2bf(xnew);
            else              xh[(a0 + row)*SN_F + col] = f2bf(xnew);
        }
    }

    if (layNext >= 0) {
        __syncthreads();
        // GEMM3: xf_out = xnew @ Win[layNext]
        f32x4 acc = {0.f,0.f,0.f,0.f};
        const unsigned short* w = wtT + OT_WINT + layNext*16384;
#pragma unroll
        for (int ks = 0; ks < 4; ks++) {
            short8 a8 = *(const short8*)&xs[rowA][ks*32 + kgrp*8];
            short8 w8 = *(const short8*)(w + col*128 + ks*32 + kgrp*8);
            acc = __builtin_amdgcn_mfma_f32_16x16x32_bf16(a8, w8, acc, 0, 0, 0);
        }
#pragma unroll
        for (int r = 0; r < 4; r++)
            xf_out[(a0 + kgrp*4 + r)*SN_F + col] = acc[r];
    }
}

// ---------------- parallel MFMA energy head: 50 blocks x 16 atoms ----------------
__global__ void k_head(const unsigned short* xh, const float* wb,
                       const unsigned short* wtT, float* epart) {
    __shared__ float red[256];
    int tid  = threadIdx.x;
    int lane = tid & 63;
    int wave = tid >> 6;          // 4 waves; wave w owns cols [w*16, w*16+16)
    int rowA = lane & 15;
    int kgrp = lane >> 4;
    int col  = wave*16 + rowA;
    int a0   = blockIdx.x * 16;
    const unsigned short* w = wtT + OT_WO1T;

    f32x4 acc = {0.f,0.f,0.f,0.f};
#pragma unroll
    for (int ks = 0; ks < 4; ks++) {
        short8 a8 = *(const short8*)(xh + (a0 + rowA)*SN_F + ks*32 + kgrp*8);
        short8 w8 = *(const short8*)(w + col*128 + ks*32 + kgrp*8);
        acc = __builtin_amdgcn_mfma_f32_16x16x32_bf16(a8, w8, acc, 0, 0, 0);
    }
    float bo1c = wb[OB_BO1 + col];
    float wo2c = wb[OB_WO2 + col];
    float e = 0.f;
#pragma unroll
    for (int r = 0; r < 4; r++) e += sspf(acc[r] + bo1c) * wo2c;

    red[tid] = e;
    __syncthreads();
    for (int wd = 128; wd > 0; wd >>= 1) {
        if (tid < wd) red[tid] += red[tid + wd];
        __syncthreads();
    }
    if (tid == 0) epart[blockIdx.x] = red[0];
}

// ---------------- final reduce (50 partials) + dtype-matched store ----------------
__global__ void k_reduce(const float* epart, const float* wb, const void* box, void* out) {
    int tid = threadIdx.x;
    float s = (tid < 50) ? epart[tid] : 0.f;
#pragma unroll
    for (int off = 32; off > 0; off >>= 1) s += __shfl_down(s, off, 64);
    if (tid == 0) {
        float v = s + (float)SN_NA * wb[OB_BO2];
        if (bfflag(box)) ((unsigned short*)out)[0] = f2bf(v);
        else             ((float*)out)[0] = v;
    }
}

__global__ void k_fail(void* out) {
    ((unsigned short*)out)[0] = 0x449A;   // bf16 1234.0 sentinel
}

extern "C" void kernel_launch(void* const* d_in, const int* in_sizes, int n_in,
                              void* d_out, int out_size, void* d_ws, size_t ws_size,
                              hipStream_t stream)
{
    const void* pos = d_in[0];
    const void* box = d_in[1];
    const int*  zn  = (const int*)d_in[2];
    const void* emb = d_in[3];

    if (ws_size < (size_t)SN_WSNEED) {
        k_fail<<<1, 1, 0, stream>>>(d_out);
        return;
    }

    char* ws = (char*)d_ws;
    int*            pcnt  = (int*)           (ws + WO_PCNT);
    int*            ncup  = (int*)           (ws + WO_NCUP);
    int*            nclo  = (int*)           (ws + WO_NCLO);
    int*            nbrp  = (int*)           (ws + WO_NBRP);
    int*            nbro  = (int*)           (ws + WO_NBRO);
    float*          pairr = (float*)         (ws + WO_PAIRR);
    float*          wb    = (float*)         (ws + WO_WB);
    unsigned short* wtT   = (unsigned short*)(ws + WO_WTT);
    unsigned short* wph   = (unsigned short*)(ws + WO_WPH);
    float*          x     = (float*)         (ws + WO_X);
    float*          xfA   = (float*)         (ws + WO_XF);
    float*          xfB   = (float*)         (ws + WO_XF2);
    unsigned short* xh    = (unsigned short*)(ws + WO_XH);
    float*          epart = (float*)         (ws + WO_EPART);

    k_setup<<<903, 256, 0, stream>>>(box,
        d_in[5], d_in[7], d_in[10], d_in[12], d_in[14], d_in[15], d_in[16],
        d_in[4], d_in[6], d_in[9], d_in[11], d_in[8], d_in[13],
        wb, wtT, pcnt, nclo);
    k_build<<<SN_NA, 256, 0, stream>>>(pos, box, pcnt, ncup, nclo, nbrp, nbro, pairr);
    k_initfilter<<<50 + 3*1024, 256, 0, stream>>>(zn, emb, box, pairr, pcnt,
                                                  wb, wtT, x, xfA, wph);

    float* xf_in = xfA;
    float* xf_out = xfB;
    for (int l = 0; l < 3; l++) {
        int layNext = (l < 2) ? (l + 1) : -1;
        k_layerM<<<50, 512, 0, stream>>>(ncup, nclo, nbrp, nbro, wph, xf_in, x,
                                         wb, wtT, l, layNext, xf_out, xh);
        float* t = xf_in; xf_in = xf_out; xf_out = t;
    }

    k_head<<<50, 256, 0, stream>>>(xh, wb, wtT, epart);
    k_reduce<<<1, 64, 0, stream>>>(epart, wb, box, d_out);
}